// Round 14
// baseline (149.944 us; speedup 1.0000x reference)
//
#include <hip/hip_runtime.h>
#include <cstdint>
#include <cstddef>

// Problem constants (fixed by the reference)
constexpr int Bc = 4, Tc = 4096, Ec = 1024, Hc = 16, Dc = 64, CHc = 64;
constexpr int NSEG = 16;              // segments (4 chunks serial, S in regs)
constexpr int SEGT = Tc / NSEG;       // 256 tokens
constexpr int NCHUNK = SEGT / CHc;    // 4

typedef __attribute__((ext_vector_type(8))) short short8;  // 8 bf16 MFMA A/B frag
typedef __attribute__((ext_vector_type(4))) float f32x4;   // MFMA C/D frag

// XOR-swizzled LDS tile addressing: [64][64] bf16, 128B rows, no pad (T2).
__device__ __forceinline__ unsigned short* sws(unsigned short* b, int row, int colbyte) {
  return (unsigned short*)((char*)b + (row << 7) + (colbyte ^ ((row & 7) << 4)));
}

__device__ __forceinline__ unsigned short f2bf(float f) {  // RNE (prep only)
  union { float f; unsigned int u; } v; v.f = f;
  return (unsigned short)((v.u + 0x7FFFu + ((v.u >> 16) & 1u)) >> 16);
}
// round-half-up pack of 2 fp32 -> u32(2xbf16) via v_perm_b32 (validated r7-r13).
__device__ __forceinline__ unsigned int pk2(float lo, float hi) {
  union { float f; unsigned int u; } a, b; a.f = lo; b.f = hi;
  return __builtin_amdgcn_perm(b.u + 0x8000u, a.u + 0x8000u, 0x07060302u);
}
__device__ __forceinline__ unsigned short h1(float f) {  // single RHU bf16
  union { float f; unsigned int u; } v; v.f = f;
  return (unsigned short)((v.u + 0x8000u) >> 16);
}
__device__ __forceinline__ float bf2f(unsigned int u16) {  // low 16 bits = bf16
  union { unsigned int u; float f; } v; v.u = u16 << 16;
  return v.f;
}
__device__ __forceinline__ float phi_elu1(float x) {   // elu(x)+1
  return x > 0.f ? x + 1.f : __expf(x);
}
__device__ __forceinline__ short8 ld8(const unsigned short* p) {
  return *reinterpret_cast<const short8*>(p);
}
__device__ __forceinline__ short8 pk8(float4 a, float4 b) {
  union { unsigned int u[4]; short8 s; } r;
  r.u[0] = pk2(a.x, a.y); r.u[1] = pk2(a.z, a.w);
  r.u[2] = pk2(b.x, b.y); r.u[3] = pk2(b.z, b.w);
  return r.s;
}
__device__ __forceinline__ void st4(unsigned short* p, float v0, float v1, float v2, float v3) {
  uint2 t; t.x = pk2(v0, v1); t.y = pk2(v2, v3);
  *reinterpret_cast<uint2*>(p) = t;
}

#define MFMA(a, b, c) __builtin_amdgcn_mfma_f32_16x16x32_bf16((a), (b), (c), 0, 0, 0)

// ---------------- prep: wqT[e][d], wkT[e][d], wvoT[d][f] (Wvo = Wv@Wo) -> bf16 ----------------
__global__ __launch_bounds__(256) void prep_weights(
    const float* __restrict__ Wq, const float* __restrict__ Wk,
    const float* __restrict__ Wv, const float* __restrict__ Wo,
    unsigned short* __restrict__ wbuf) {
  __shared__ float s_wvT[4096];  // [g][f] = Wv[f][g]
  __shared__ float s_wo[4096];   // [g][d] = Wo[g][d]
  const int tid = threadIdx.x;
  const int i = blockIdx.x * 256 + tid;          // 0..4095
  for (int j = tid; j < 4096; j += 256) {
    s_wvT[(j & 63) * 64 + (j >> 6)] = Wv[j];
    s_wo[j] = Wo[j];
  }
  __syncthreads();
  const int r = i >> 6, c = i & 63;
  wbuf[c * 64 + r] = f2bf(Wq[i]);                // wqT[e][d] = Wq[d][e]
  wbuf[4096 + c * 64 + r] = f2bf(Wk[i]);         // wkT
  float acc = 0.f;                               // wvoT[d][f] = (Wv@Wo)[f][d];  d=r, f=c
  for (int g = 0; g < 64; ++g)
    acc += s_wvT[g * 64 + c] * s_wo[g * 64 + r];
  wbuf[8192 + i] = f2bf(acc);
}

// ---------------- pass1: per-SEGMENT KV = sum_t phi(k)^T v' -> bf16 P-layout ----------------
// grid (64 bh, 15 sg); 4 chunks serial; kT/vT dbuf -> 1 barrier/chunk (r10, proven).
__global__ __launch_bounds__(256, 3) void pass1_kvseg(
    const float* __restrict__ x, const unsigned short* __restrict__ wbuf,
    unsigned short* __restrict__ kvseg) {
  __shared__ unsigned short s_kT[2][4096];   // phi(k)^T [e][t]  (swizzled, dbuf)
  __shared__ unsigned short s_vT[2][4096];   // v'^T [d][t]      (swizzled, dbuf)
  const int tid = threadIdx.x, w = tid >> 6, lane = tid & 63, lr = lane & 15, lq = lane >> 4;
  const int bh = blockIdx.x, sg = blockIdx.y, b = bh >> 4, h = bh & 15;
  const float* xbase = x + ((size_t)b * Tc + (size_t)sg * SEGT) * Ec + h * Dc;
  const unsigned short* wkT = wbuf + 4096;
  const unsigned short* wvoT = wbuf + 8192;
  const f32x4 Z = {0.f, 0.f, 0.f, 0.f};

  short8 bwk[4][2], bwv[4][2];   // B-side weight frags (rows e / d = c*16+lr)
#pragma unroll
  for (int c = 0; c < 4; ++c)
#pragma unroll
    for (int kk = 0; kk < 2; ++kk) {
      bwk[c][kk] = ld8(wkT + (c * 16 + lr) * 64 + kk * 32 + lq * 8);
      bwv[c][kk] = ld8(wvoT + (c * 16 + lr) * 64 + kk * 32 + lq * 8);
    }

  const float* xr = xbase + (size_t)(w * 16 + lr) * Ec + lq * 8;
  float4 p0 = ((const float4*)xr)[0], p1 = ((const float4*)xr)[1];
  float4 p2 = ((const float4*)(xr + 32))[0], p3 = ((const float4*)(xr + 32))[1];

  f32x4 sacc[4] = {Z, Z, Z, Z};
#pragma unroll
  for (int ci = 0; ci < NCHUNK; ++ci) {
    unsigned short* skT = s_kT[ci & 1];
    unsigned short* svT = s_vT[ci & 1];
    short8 xa0 = pk8(p0, p1), xa1 = pk8(p2, p3);
    if (ci < NCHUNK - 1) {
      const float* nr = xbase + (size_t)((ci + 1) * CHc + w * 16 + lr) * Ec + lq * 8;
      p0 = ((const float4*)nr)[0]; p1 = ((const float4*)nr)[1];
      p2 = ((const float4*)(nr + 32))[0]; p3 = ((const float4*)(nr + 32))[1];
    }
    f32x4 ak[4] = {Z, Z, Z, Z}, av[4] = {Z, Z, Z, Z};
    __builtin_amdgcn_s_setprio(1);
#pragma unroll
    for (int c = 0; c < 4; ++c) {
      ak[c] = MFMA(xa0, bwk[c][0], ak[c]); ak[c] = MFMA(xa1, bwk[c][1], ak[c]);  // k[t][e]
      av[c] = MFMA(xa0, bwv[c][0], av[c]); av[c] = MFMA(xa1, bwv[c][1], av[c]);  // v'[t][d]
    }
    __builtin_amdgcn_s_setprio(0);
#pragma unroll
    for (int c = 0; c < 4; ++c) {   // transposed b64-packed stores -> [e][t] / [d][t]
      st4(sws(skT, c * 16 + lr, w * 32 + lq * 8),
          phi_elu1(ak[c][0]), phi_elu1(ak[c][1]), phi_elu1(ak[c][2]), phi_elu1(ak[c][3]));
      st4(sws(svT, c * 16 + lr, w * 32 + lq * 8), av[c][0], av[c][1], av[c][2], av[c][3]);
    }
    __syncthreads();  // one barrier per chunk (dbuf)
    short8 akt0 = ld8(sws(skT, w * 16 + lr, lq * 16));
    short8 akt1 = ld8(sws(skT, w * 16 + lr, 64 + lq * 16));
    __builtin_amdgcn_s_setprio(1);
#pragma unroll
    for (int c = 0; c < 4; ++c) {   // KV[e][d] += sum_t kT[e][t] vT[d][t]
      sacc[c] = MFMA(akt0, ld8(sws(svT, c * 16 + lr, lq * 16)), sacc[c]);
      sacc[c] = MFMA(akt1, ld8(sws(svT, c * 16 + lr, 64 + lq * 16)), sacc[c]);
    }
    __builtin_amdgcn_s_setprio(0);
  }

  unsigned short* dst = kvseg + ((size_t)bh * NSEG + sg) * 4096 + (w * 64 + lane) * 16;
#pragma unroll
  for (int c = 0; c < 4; ++c) {
    uint2 t; t.x = pk2(sacc[c][0], sacc[c][1]); t.y = pk2(sacc[c][2], sacc[c][3]);
    *reinterpret_cast<uint2*>(dst + c * 4) = t;
  }
}

// ---------------- pass3: 5-tile (40KB -> 4 blocks/CU), VGPR capped 128 ----------------
// s_k/s_kT eliminated: a_k/a_t are produced IN-WAVE in stage A via the shared scratch tile
// (akt acc = kT own e-strip; ack acc = k own t-strip; 16 b16 stores + 2 ld8 each, DS in-order,
// per-wave-private region -> no barriers). bwv demoted to per-c transient global ld8 (L2-hot).
__global__ __launch_bounds__(256, 4) void pass3_main(
    const float* __restrict__ x, const unsigned short* __restrict__ wbuf,
    const unsigned short* __restrict__ kvseg, float* __restrict__ out) {
  __shared__ unsigned short s_x [4096];   // x chunk [t][d]; attn after stage B; restaged at C end
  __shared__ unsigned short s_q [4096];   // q [t][e]
  __shared__ unsigned short s_vT[4096];   // v'^T [d][t]
  __shared__ unsigned short s_Sb[4096];   // S^T [d][e] snapshot (pre-update)
  __shared__ unsigned short s_scr[4096];  // per-wave scratch: kT then k (in-wave transposes)

  const int tid = threadIdx.x, w = tid >> 6, lane = tid & 63, lr = lane & 15, lq = lane >> 4;
  const int bh = blockIdx.x, sg = blockIdx.y, b = bh >> 4, h = bh & 15;
  const float* xbase = x + ((size_t)b * Tc + (size_t)sg * SEGT) * Ec + h * Dc;
  float* obase = out + ((size_t)b * Tc + (size_t)sg * SEGT) * Ec + h * Dc;
  const unsigned short* wqT = wbuf;
  const unsigned short* wkT = wbuf + 4096;
  const unsigned short* wvoT = wbuf + 8192;
  const int sr = tid >> 2, sc = tid & 3;
  const f32x4 Z = {0.f, 0.f, 0.f, 0.f};

  // S-init: exclusive prefix over predecessor segment-KVs (P-layout, coalesced, L2-resident)
  f32x4 sacc[4] = {Z, Z, Z, Z};
  {
    const unsigned short* kvb = kvseg + (size_t)bh * NSEG * 4096 + (w * 64 + lane) * 16;
    for (int sp = 0; sp < sg; ++sp) {
      const unsigned short* p = kvb + (size_t)sp * 4096;
#pragma unroll
      for (int c = 0; c < 4; ++c) {
        uint2 u = *reinterpret_cast<const uint2*>(p + c * 4);
        sacc[c][0] += bf2f(u.x & 0xFFFFu); sacc[c][1] += bf2f(u.x >> 16);
        sacc[c][2] += bf2f(u.y & 0xFFFFu); sacc[c][3] += bf2f(u.y >> 16);
      }
    }
  }

  // resident weight fragments: awq/awk (A-side, own e-strip) + bwk (B-side) = 12 frags
  short8 awq[2], awk[2], bwk[4][2];
#pragma unroll
  for (int kk = 0; kk < 2; ++kk) {
    awq[kk] = ld8(wqT + (w * 16 + lr) * 64 + kk * 32 + lq * 8);
    awk[kk] = ld8(wkT + (w * 16 + lr) * 64 + kk * 32 + lq * 8);
  }
#pragma unroll
  for (int c = 0; c < 4; ++c)
#pragma unroll
    for (int kk = 0; kk < 2; ++kk)
      bwk[c][kk] = ld8(wkT + (c * 16 + lr) * 64 + kk * 32 + lq * 8);

  {  // stage chunk0 x -> LDS (swizzled)
    const float4* xf = (const float4*)(xbase + (size_t)sr * Ec + sc * 16);
    float4 f0 = xf[0], f1 = xf[1], f2 = xf[2], f3 = xf[3];
    *(short8*)sws(s_x, sr, sc * 32) = pk8(f0, f1);
    *(short8*)sws(s_x, sr, sc * 32 + 16) = pk8(f2, f3);
  }
  __syncthreads();  // x ready

#pragma unroll
  for (int ci = 0; ci < NCHUNK; ++ci) {
    // ---- stage A ----
    short8 xw0 = ld8(sws(s_x, w * 16 + lr, lq * 16));        // own strip (A-side)
    short8 xw1 = ld8(sws(s_x, w * 16 + lr, 64 + lq * 16));
#pragma unroll
    for (int c = 0; c < 4; ++c)                               // S snapshot -> s_Sb[d][e]
      st4(sws(s_Sb, c * 16 + lr, w * 32 + lq * 8), sacc[c][0], sacc[c][1], sacc[c][2], sacc[c][3]);

    // q (transposed acc -> s_q rows) and kT (own e-strip -> scratch), streamed per c
    __builtin_amdgcn_s_setprio(1);
#pragma unroll
    for (int c = 0; c < 4; ++c) {
      short8 xb0 = ld8(sws(s_x, c * 16 + lr, lq * 16));
      short8 xb1 = ld8(sws(s_x, c * 16 + lr, 64 + lq * 16));
      f32x4 aqt = Z, akt = Z;
      aqt = MFMA(awq[0], xb0, aqt); aqt = MFMA(awq[1], xb1, aqt);   // qT[e][t]
      akt = MFMA(awk[0], xb0, akt); akt = MFMA(awk[1], xb1, akt);   // kT[e][t']
      st4(sws(s_q, c * 16 + lr, w * 32 + lq * 8),
          phi_elu1(aqt[0]), phi_elu1(aqt[1]), phi_elu1(aqt[2]), phi_elu1(aqt[3]));
#pragma unroll
      for (int j = 0; j < 4; ++j)    // kT[e = w16+lq*4+j][t' = c*16+lr] -> scratch (own band)
        *sws(s_scr, w * 16 + lq * 4 + j, (c * 16 + lr) * 2) = h1(phi_elu1(akt[j]));
    }
    __builtin_amdgcn_s_setprio(0);
    short8 a_t0 = ld8(sws(s_scr, w * 16 + lr, lq * 16));      // kT own-strip frags
    short8 a_t1 = ld8(sws(s_scr, w * 16 + lr, 64 + lq * 16));

    // k (own t-strip -> scratch, overwrites; DS in-order protects a_t reads above)
    __builtin_amdgcn_s_setprio(1);
#pragma unroll
    for (int c = 0; c < 4; ++c) {
      f32x4 ack = Z;
      ack = MFMA(xw0, bwk[c][0], ack); ack = MFMA(xw1, bwk[c][1], ack);  // k[t][e]
#pragma unroll
      for (int j = 0; j < 4; ++j)    // k[t = w16+lq*4+j][e = c*16+lr] -> scratch (own band)
        *sws(s_scr, w * 16 + lq * 4 + j, (c * 16 + lr) * 2) = h1(phi_elu1(ack[j]));
    }
    __builtin_amdgcn_s_setprio(0);
    short8 a_k0 = ld8(sws(s_scr, w * 16 + lr, lq * 16));      // k own-strip frags
    short8 a_k1 = ld8(sws(s_scr, w * 16 + lr, 64 + lq * 16));

    // v' (bwv from global per c, L2-hot 24KB shared by all blocks)
    __builtin_amdgcn_s_setprio(1);
#pragma unroll
    for (int c = 0; c < 4; ++c) {
      short8 bv0 = ld8(wvoT + (c * 16 + lr) * 64 + lq * 8);
      short8 bv1 = ld8(wvoT + (c * 16 + lr) * 64 + 32 + lq * 8);
      f32x4 acv = Z;
      acv = MFMA(xw0, bv0, acv); acv = MFMA(xw1, bv1, acv);   // v'[t][d]
      st4(sws(s_vT, c * 16 + lr, w * 32 + lq * 8), acv[0], acv[1], acv[2], acv[3]);
    }
    __builtin_amdgcn_s_setprio(0);
    __syncthreads();  // B1

    // ---- stage B: attnT = k q^T (masked); o_inter = q@S; S += kT@v' ----
    float4 pf0, pf1, pf2, pf3;      // prefetch next chunk's x (consumed at restage)
    if (ci < NCHUNK - 1) {
      const float4* xf = (const float4*)(xbase + (size_t)((ci + 1) * CHc + sr) * Ec + sc * 16);
      pf0 = xf[0]; pf1 = xf[1]; pf2 = xf[2]; pf3 = xf[3];
    }
    short8 a_q0 = ld8(sws(s_q, w * 16 + lr, lq * 16));
    short8 a_q1 = ld8(sws(s_q, w * 16 + lr, 64 + lq * 16));
    f32x4 aat[4] = {Z, Z, Z, Z}, ao[4] = {Z, Z, Z, Z};
    __builtin_amdgcn_s_setprio(1);
#pragma unroll
    for (int c = 0; c < 4; ++c) {
      const int row = c * 16 + lr;
      aat[c]  = MFMA(a_k0, ld8(sws(s_q, row, lq * 16)), aat[c]);       // attnT[t'][t]
      aat[c]  = MFMA(a_k1, ld8(sws(s_q, row, 64 + lq * 16)), aat[c]);
      ao[c]   = MFMA(a_q0, ld8(sws(s_Sb, row, lq * 16)), ao[c]);       // o_inter = q @ S
      ao[c]   = MFMA(a_q1, ld8(sws(s_Sb, row, 64 + lq * 16)), ao[c]);
      sacc[c] = MFMA(a_t0, ld8(sws(s_vT, row, lq * 16)), sacc[c]);     // S += kT @ v'
      sacc[c] = MFMA(a_t1, ld8(sws(s_vT, row, 64 + lq * 16)), sacc[c]);
    }
    __builtin_amdgcn_s_setprio(0);
    // masked attnT (acc row t'=w16+lq*4+j, col t=c*16+lr) -> store attn[t][t'] into s_x
#pragma unroll
    for (int c = 0; c < 4; ++c) {
      int t = c * 16 + lr, tp = w * 16 + lq * 4;
      float m0 = (tp + 0 <= t) ? aat[c][0] : 0.f;
      float m1 = (tp + 1 <= t) ? aat[c][1] : 0.f;
      float m2 = (tp + 2 <= t) ? aat[c][2] : 0.f;
      float m3 = (tp + 3 <= t) ? aat[c][3] : 0.f;
      st4(sws(s_x, t, tp * 2), m0, m1, m2, m3);
    }
    __syncthreads();  // B2

    // ---- stage C: o += attn@v'; write out from fp32 acc; restage next x ----
    short8 a_a0 = ld8(sws(s_x, w * 16 + lr, lq * 16));
    short8 a_a1 = ld8(sws(s_x, w * 16 + lr, 64 + lq * 16));
    __builtin_amdgcn_s_setprio(1);
#pragma unroll
    for (int c = 0; c < 4; ++c) {
      const int row = c * 16 + lr;
      ao[c] = MFMA(a_a0, ld8(sws(s_vT, row, lq * 16)), ao[c]);
      ao[c] = MFMA(a_a1, ld8(sws(s_vT, row, 64 + lq * 16)), ao[c]);
    }
    __builtin_amdgcn_s_setprio(0);
    float* orow = obase + (size_t)(ci * CHc) * Ec;
#pragma unroll
    for (int c = 0; c < 4; ++c)
#pragma unroll
      for (int j = 0; j < 4; ++j)
        orow[(size_t)(w * 16 + lq * 4 + j) * Ec + c * 16 + lr] = ao[c][j];
    if (ci < NCHUNK - 1) {  // restage: per-wave row-disjoint, read-before-write in-wave
      *(short8*)sws(s_x, sr, sc * 32) = pk8(pf0, pf1);
      *(short8*)sws(s_x, sr, sc * 32 + 16) = pk8(pf2, pf3);
    }
    __syncthreads();  // B3
  }
}

extern "C" void kernel_launch(void* const* d_in, const int* in_sizes, int n_in,
                              void* d_out, int out_size, void* d_ws, size_t ws_size,
                              hipStream_t stream) {
  const float* x  = (const float*)d_in[0];
  const float* Wq = (const float*)d_in[1];
  const float* Wk = (const float*)d_in[2];
  const float* Wv = (const float*)d_in[3];
  const float* Wo = (const float*)d_in[4];
  float* out = (float*)d_out;

  unsigned short* wbuf  = (unsigned short*)d_ws;                   // 24 KB used (reserve 32 KB)
  unsigned short* kvseg = (unsigned short*)((char*)d_ws + 32768);  // 8 MB bf16, P-layout

  prep_weights<<<dim3(16), dim3(256), 0, stream>>>(Wq, Wk, Wv, Wo, wbuf);
  pass1_kvseg<<<dim3(64, NSEG - 1), dim3(256), 0, stream>>>(x, wbuf, kvseg);
  pass3_main<<<dim3(64, NSEG), dim3(256), 0, stream>>>(x, wbuf, kvseg, out);
}

// Round 15
// 76.656 us; speedup vs baseline: 1.9561x; 1.9561x over previous
//
#include <hip/hip_runtime.h>
#include <cstdint>
#include <cstddef>

// Problem constants (fixed by the reference)
constexpr int Bc = 4, Tc = 4096, Ec = 1024, Hc = 16, Dc = 64, CHc = 64;
constexpr int NSEG = 16;              // segments (4 chunks serial, S in regs)
constexpr int SEGT = Tc / NSEG;       // 256 tokens
constexpr int NCHUNK = SEGT / CHc;    // 4

typedef __attribute__((ext_vector_type(8))) short short8;  // 8 bf16 MFMA A/B frag
typedef __attribute__((ext_vector_type(4))) float f32x4;   // MFMA C/D frag

// XCD-aware bijective swizzle (T1): consecutive work-ids (same-sg bh runs, which share
// x rows) land on the SAME XCD's L2. nwg must be divisible by 8 (960/1024 both are).
__device__ __forceinline__ int xcd_swz(int i, int nwg) {
  return (i & 7) * (nwg >> 3) + (i >> 3);
}

// XOR-swizzled LDS tile addressing: [64][64] bf16, 128B rows, no pad (T2).
__device__ __forceinline__ unsigned short* sws(unsigned short* b, int row, int colbyte) {
  return (unsigned short*)((char*)b + (row << 7) + (colbyte ^ ((row & 7) << 4)));
}

__device__ __forceinline__ unsigned short f2bf(float f) {  // RNE (prep only)
  union { float f; unsigned int u; } v; v.f = f;
  return (unsigned short)((v.u + 0x7FFFu + ((v.u >> 16) & 1u)) >> 16);
}
// round-half-up pack of 2 fp32 -> u32(2xbf16) via v_perm_b32 (validated r7-r14).
__device__ __forceinline__ unsigned int pk2(float lo, float hi) {
  union { float f; unsigned int u; } a, b; a.f = lo; b.f = hi;
  return __builtin_amdgcn_perm(b.u + 0x8000u, a.u + 0x8000u, 0x07060302u);
}
__device__ __forceinline__ float bf2f(unsigned int u16) {  // low 16 bits = bf16
  union { unsigned int u; float f; } v; v.u = u16 << 16;
  return v.f;
}
__device__ __forceinline__ float phi_elu1(float x) {   // elu(x)+1
  return x > 0.f ? x + 1.f : __expf(x);
}
__device__ __forceinline__ short8 ld8(const unsigned short* p) {
  return *reinterpret_cast<const short8*>(p);
}
__device__ __forceinline__ short8 pk8(float4 a, float4 b) {
  union { unsigned int u[4]; short8 s; } r;
  r.u[0] = pk2(a.x, a.y); r.u[1] = pk2(a.z, a.w);
  r.u[2] = pk2(b.x, b.y); r.u[3] = pk2(b.z, b.w);
  return r.s;
}
__device__ __forceinline__ void st4(unsigned short* p, float v0, float v1, float v2, float v3) {
  uint2 t; t.x = pk2(v0, v1); t.y = pk2(v2, v3);
  *reinterpret_cast<uint2*>(p) = t;
}

#define MFMA(a, b, c) __builtin_amdgcn_mfma_f32_16x16x32_bf16((a), (b), (c), 0, 0, 0)

// ---------------- prep: wqT[e][d], wkT[e][d], wvoT[d][f] (Wvo = Wv@Wo) -> bf16 ----------------
__global__ __launch_bounds__(256) void prep_weights(
    const float* __restrict__ Wq, const float* __restrict__ Wk,
    const float* __restrict__ Wv, const float* __restrict__ Wo,
    unsigned short* __restrict__ wbuf) {
  __shared__ float s_wvT[4096];  // [g][f] = Wv[f][g]
  __shared__ float s_wo[4096];   // [g][d] = Wo[g][d]
  const int tid = threadIdx.x;
  const int i = blockIdx.x * 256 + tid;          // 0..4095
  for (int j = tid; j < 4096; j += 256) {
    s_wvT[(j & 63) * 64 + (j >> 6)] = Wv[j];
    s_wo[j] = Wo[j];
  }
  __syncthreads();
  const int r = i >> 6, c = i & 63;
  wbuf[c * 64 + r] = f2bf(Wq[i]);                // wqT[e][d] = Wq[d][e]
  wbuf[4096 + c * 64 + r] = f2bf(Wk[i]);         // wkT
  float acc = 0.f;                               // wvoT[d][f] = (Wv@Wo)[f][d];  d=r, f=c
  for (int g = 0; g < 64; ++g)
    acc += s_wvT[g * 64 + c] * s_wo[g * 64 + r];
  wbuf[8192 + i] = f2bf(acc);
}

// ---------------- pass1: per-SEGMENT KV = sum_t phi(k)^T v' -> bf16 P-layout ----------------
// 960 blocks (segment 15's KV has no consumer), XCD-swizzled; 4 chunks serial; kT/vT dbuf ->
// 1 barrier/chunk; x prefetched one chunk ahead; weight frags amortized (r10, proven).
__global__ __launch_bounds__(256, 3) void pass1_kvseg(
    const float* __restrict__ x, const unsigned short* __restrict__ wbuf,
    unsigned short* __restrict__ kvseg) {
  __shared__ unsigned short s_kT[2][4096];   // phi(k)^T [e][t]  (swizzled, dbuf)
  __shared__ unsigned short s_vT[2][4096];   // v'^T [d][t]      (swizzled, dbuf)
  const int tid = threadIdx.x, w = tid >> 6, lane = tid & 63, lr = lane & 15, lq = lane >> 4;
  const int id = xcd_swz(blockIdx.x, 64 * (NSEG - 1));
  const int bh = id & 63, sg = id >> 6, b = bh >> 4, h = bh & 15;
  const float* xbase = x + ((size_t)b * Tc + (size_t)sg * SEGT) * Ec + h * Dc;
  const unsigned short* wkT = wbuf + 4096;
  const unsigned short* wvoT = wbuf + 8192;
  const f32x4 Z = {0.f, 0.f, 0.f, 0.f};

  short8 bwk[4][2], bwv[4][2];   // B-side weight frags (rows e / d = c*16+lr)
#pragma unroll
  for (int c = 0; c < 4; ++c)
#pragma unroll
    for (int kk = 0; kk < 2; ++kk) {
      bwk[c][kk] = ld8(wkT + (c * 16 + lr) * 64 + kk * 32 + lq * 8);
      bwv[c][kk] = ld8(wvoT + (c * 16 + lr) * 64 + kk * 32 + lq * 8);
    }

  const float* xr = xbase + (size_t)(w * 16 + lr) * Ec + lq * 8;
  float4 p0 = ((const float4*)xr)[0], p1 = ((const float4*)xr)[1];
  float4 p2 = ((const float4*)(xr + 32))[0], p3 = ((const float4*)(xr + 32))[1];

  f32x4 sacc[4] = {Z, Z, Z, Z};
#pragma unroll
  for (int ci = 0; ci < NCHUNK; ++ci) {
    unsigned short* skT = s_kT[ci & 1];
    unsigned short* svT = s_vT[ci & 1];
    short8 xa0 = pk8(p0, p1), xa1 = pk8(p2, p3);
    if (ci < NCHUNK - 1) {   // prefetch next chunk's x (hidden under this chunk)
      const float* nr = xbase + (size_t)((ci + 1) * CHc + w * 16 + lr) * Ec + lq * 8;
      p0 = ((const float4*)nr)[0]; p1 = ((const float4*)nr)[1];
      p2 = ((const float4*)(nr + 32))[0]; p3 = ((const float4*)(nr + 32))[1];
    }
    f32x4 ak[4] = {Z, Z, Z, Z}, av[4] = {Z, Z, Z, Z};
    __builtin_amdgcn_s_setprio(1);
#pragma unroll
    for (int c = 0; c < 4; ++c) {
      ak[c] = MFMA(xa0, bwk[c][0], ak[c]); ak[c] = MFMA(xa1, bwk[c][1], ak[c]);  // k[t][e]
      av[c] = MFMA(xa0, bwv[c][0], av[c]); av[c] = MFMA(xa1, bwv[c][1], av[c]);  // v'[t][d]
    }
    __builtin_amdgcn_s_setprio(0);
#pragma unroll
    for (int c = 0; c < 4; ++c) {   // transposed b64-packed stores -> [e][t] / [d][t]
      st4(sws(skT, c * 16 + lr, w * 32 + lq * 8),
          phi_elu1(ak[c][0]), phi_elu1(ak[c][1]), phi_elu1(ak[c][2]), phi_elu1(ak[c][3]));
      st4(sws(svT, c * 16 + lr, w * 32 + lq * 8), av[c][0], av[c][1], av[c][2], av[c][3]);
    }
    __syncthreads();  // one barrier per chunk (dbuf)
    short8 akt0 = ld8(sws(skT, w * 16 + lr, lq * 16));
    short8 akt1 = ld8(sws(skT, w * 16 + lr, 64 + lq * 16));
    __builtin_amdgcn_s_setprio(1);
#pragma unroll
    for (int c = 0; c < 4; ++c) {   // KV[e][d] += sum_t kT[e][t] vT[d][t]
      sacc[c] = MFMA(akt0, ld8(sws(svT, c * 16 + lr, lq * 16)), sacc[c]);
      sacc[c] = MFMA(akt1, ld8(sws(svT, c * 16 + lr, 64 + lq * 16)), sacc[c]);
    }
    __builtin_amdgcn_s_setprio(0);
  }

  // P-layout store: 4x uint2, 32B contiguous per thread, 2KB per wave
  unsigned short* dst = kvseg + ((size_t)bh * NSEG + sg) * 4096 + (w * 64 + lane) * 16;
#pragma unroll
  for (int c = 0; c < 4; ++c) {
    uint2 t; t.x = pk2(sacc[c][0], sacc[c][1]); t.y = pk2(sacc[c][2], sacc[c][3]);
    *reinterpret_cast<uint2*>(dst + c * 4) = t;
  }
}

// ---------------- pass3: r10 structure (proven 46.3us) + XCD swizzle ----------------
__global__ __launch_bounds__(256, 2) void pass3_main(
    const float* __restrict__ x, const unsigned short* __restrict__ wbuf,
    const unsigned short* __restrict__ kvseg, float* __restrict__ out) {
  __shared__ unsigned short s_x [4096];   // x chunk [t][d]; attn after stage B; restaged at C end
  __shared__ unsigned short s_q [4096];   // q [t][e]
  __shared__ unsigned short s_k [4096];   // k [t'][e]
  __shared__ unsigned short s_kT[4096];   // phi(k)^T [e][t]
  __shared__ unsigned short s_vT[4096];   // v'^T [d][t]
  __shared__ unsigned short s_Sb[4096];   // S^T [d][e] snapshot (pre-update)

  const int tid = threadIdx.x, w = tid >> 6, lane = tid & 63, lr = lane & 15, lq = lane >> 4;
  const int id = xcd_swz(blockIdx.x, 64 * NSEG);
  const int bh = id & 63, sg = id >> 6, b = bh >> 4, h = bh & 15;
  const float* xbase = x + ((size_t)b * Tc + (size_t)sg * SEGT) * Ec + h * Dc;
  float* obase = out + ((size_t)b * Tc + (size_t)sg * SEGT) * Ec + h * Dc;
  const unsigned short* wqT = wbuf;
  const unsigned short* wkT = wbuf + 4096;
  const unsigned short* wvoT = wbuf + 8192;
  const int sr = tid >> 2, sc = tid & 3;
  const f32x4 Z = {0.f, 0.f, 0.f, 0.f};

  // S-init: exclusive prefix over predecessor segment-KVs (P-layout, coalesced, L2-resident)
  f32x4 sacc[4] = {Z, Z, Z, Z};
  {
    const unsigned short* kvb = kvseg + (size_t)bh * NSEG * 4096 + (w * 64 + lane) * 16;
    for (int sp = 0; sp < sg; ++sp) {
      const unsigned short* p = kvb + (size_t)sp * 4096;
#pragma unroll
      for (int c = 0; c < 4; ++c) {
        uint2 u = *reinterpret_cast<const uint2*>(p + c * 4);
        sacc[c][0] += bf2f(u.x & 0xFFFFu); sacc[c][1] += bf2f(u.x >> 16);
        sacc[c][2] += bf2f(u.y & 0xFFFFu); sacc[c][3] += bf2f(u.y >> 16);
      }
    }
  }

  // weight fragments in registers
  short8 awq[2], awk[2], bwk[4][2], bwv[4][2];
#pragma unroll
  for (int kk = 0; kk < 2; ++kk) {
    awq[kk] = ld8(wqT + (w * 16 + lr) * 64 + kk * 32 + lq * 8);   // A-side rows e (w-strip)
    awk[kk] = ld8(wkT + (w * 16 + lr) * 64 + kk * 32 + lq * 8);
  }
#pragma unroll
  for (int c = 0; c < 4; ++c)
#pragma unroll
    for (int kk = 0; kk < 2; ++kk) {
      bwk[c][kk] = ld8(wkT + (c * 16 + lr) * 64 + kk * 32 + lq * 8);   // B-side rows e
      bwv[c][kk] = ld8(wvoT + (c * 16 + lr) * 64 + kk * 32 + lq * 8);  // B-side rows d
    }

  {  // stage chunk0 x -> LDS (swizzled)
    const float4* xf = (const float4*)(xbase + (size_t)sr * Ec + sc * 16);
    float4 f0 = xf[0], f1 = xf[1], f2 = xf[2], f3 = xf[3];
    *(short8*)sws(s_x, sr, sc * 32) = pk8(f0, f1);
    *(short8*)sws(s_x, sr, sc * 32 + 16) = pk8(f2, f3);
  }
  __syncthreads();  // x ready

#pragma unroll
  for (int ci = 0; ci < NCHUNK; ++ci) {
    // prefetch next chunk's x into regs (consumed at end of stage C)
    float4 pf0, pf1, pf2, pf3;
    if (ci < NCHUNK - 1) {
      const float4* xf = (const float4*)(xbase + (size_t)((ci + 1) * CHc + sr) * Ec + sc * 16);
      pf0 = xf[0]; pf1 = xf[1]; pf2 = xf[2]; pf3 = xf[3];
    }

    // ---- stage A: 4 projections; all stores transposed b64-packed ----
    short8 xb[4][2];
#pragma unroll
    for (int c = 0; c < 4; ++c) {
      xb[c][0] = ld8(sws(s_x, c * 16 + lr, lq * 16));
      xb[c][1] = ld8(sws(s_x, c * 16 + lr, 64 + lq * 16));
    }
    short8 xw0 = ld8(sws(s_x, w * 16 + lr, lq * 16));        // own strip (A-side)
    short8 xw1 = ld8(sws(s_x, w * 16 + lr, 64 + lq * 16));
#pragma unroll
    for (int c = 0; c < 4; ++c)                               // S snapshot -> s_Sb[d][e]
      st4(sws(s_Sb, c * 16 + lr, w * 32 + lq * 8), sacc[c][0], sacc[c][1], sacc[c][2], sacc[c][3]);

    f32x4 aqt[4] = {Z, Z, Z, Z}, akt[4] = {Z, Z, Z, Z}, ack[4] = {Z, Z, Z, Z}, acv[4] = {Z, Z, Z, Z};
    __builtin_amdgcn_s_setprio(1);
#pragma unroll
    for (int c = 0; c < 4; ++c) {
      aqt[c] = MFMA(awq[0], xb[c][0], aqt[c]); aqt[c] = MFMA(awq[1], xb[c][1], aqt[c]);  // qT[e][t]
      akt[c] = MFMA(awk[0], xb[c][0], akt[c]); akt[c] = MFMA(awk[1], xb[c][1], akt[c]);  // kT[e][t']
      ack[c] = MFMA(xw0, bwk[c][0], ack[c]);   ack[c] = MFMA(xw1, bwk[c][1], ack[c]);    // k[t][e]
      acv[c] = MFMA(xw0, bwv[c][0], acv[c]);   acv[c] = MFMA(xw1, bwv[c][1], acv[c]);    // v'[t][d]
    }
    __builtin_amdgcn_s_setprio(0);
#pragma unroll
    for (int c = 0; c < 4; ++c) {
      const int row = c * 16 + lr, cb = w * 32 + lq * 8;
      st4(sws(s_q, row, cb), phi_elu1(aqt[c][0]), phi_elu1(aqt[c][1]), phi_elu1(aqt[c][2]), phi_elu1(aqt[c][3]));
      st4(sws(s_k, row, cb), phi_elu1(akt[c][0]), phi_elu1(akt[c][1]), phi_elu1(akt[c][2]), phi_elu1(akt[c][3]));
      st4(sws(s_kT, row, cb), phi_elu1(ack[c][0]), phi_elu1(ack[c][1]), phi_elu1(ack[c][2]), phi_elu1(ack[c][3]));
      st4(sws(s_vT, row, cb), acv[c][0], acv[c][1], acv[c][2], acv[c][3]);
    }
    __syncthreads();  // B1

    // ---- stage B: attnT = k q^T (masked); o_inter = q@S; S += kT@v' ----
    short8 a_q0 = ld8(sws(s_q, w * 16 + lr, lq * 16));
    short8 a_q1 = ld8(sws(s_q, w * 16 + lr, 64 + lq * 16));
    short8 a_k0 = ld8(sws(s_k, w * 16 + lr, lq * 16));
    short8 a_k1 = ld8(sws(s_k, w * 16 + lr, 64 + lq * 16));
    short8 a_t0 = ld8(sws(s_kT, w * 16 + lr, lq * 16));
    short8 a_t1 = ld8(sws(s_kT, w * 16 + lr, 64 + lq * 16));
    f32x4 aat[4] = {Z, Z, Z, Z}, ao[4] = {Z, Z, Z, Z};
    __builtin_amdgcn_s_setprio(1);
#pragma unroll
    for (int c = 0; c < 4; ++c) {
      const int row = c * 16 + lr;
      aat[c]  = MFMA(a_k0, ld8(sws(s_q, row, lq * 16)), aat[c]);
      aat[c]  = MFMA(a_k1, ld8(sws(s_q, row, 64 + lq * 16)), aat[c]);
      ao[c]   = MFMA(a_q0, ld8(sws(s_Sb, row, lq * 16)), ao[c]);
      ao[c]   = MFMA(a_q1, ld8(sws(s_Sb, row, 64 + lq * 16)), ao[c]);
      sacc[c] = MFMA(a_t0, ld8(sws(s_vT, row, lq * 16)), sacc[c]);
      sacc[c] = MFMA(a_t1, ld8(sws(s_vT, row, 64 + lq * 16)), sacc[c]);
    }
    __builtin_amdgcn_s_setprio(0);
    // masked attnT (acc row t'=w16+lq*4+j, col t=c*16+lr) -> store attn[t][t'] into s_x
#pragma unroll
    for (int c = 0; c < 4; ++c) {
      int t = c * 16 + lr, tp = w * 16 + lq * 4;
      float m0 = (tp + 0 <= t) ? aat[c][0] : 0.f;
      float m1 = (tp + 1 <= t) ? aat[c][1] : 0.f;
      float m2 = (tp + 2 <= t) ? aat[c][2] : 0.f;
      float m3 = (tp + 3 <= t) ? aat[c][3] : 0.f;
      st4(sws(s_x, t, tp * 2), m0, m1, m2, m3);
    }
    __syncthreads();  // B2

    // ---- stage C: o += attn@v'; write out from fp32 acc; restage next x ----
    short8 a_a0 = ld8(sws(s_x, w * 16 + lr, lq * 16));
    short8 a_a1 = ld8(sws(s_x, w * 16 + lr, 64 + lq * 16));
    __builtin_amdgcn_s_setprio(1);
#pragma unroll
    for (int c = 0; c < 4; ++c) {
      const int row = c * 16 + lr;
      ao[c] = MFMA(a_a0, ld8(sws(s_vT, row, lq * 16)), ao[c]);
      ao[c] = MFMA(a_a1, ld8(sws(s_vT, row, 64 + lq * 16)), ao[c]);
    }
    __builtin_amdgcn_s_setprio(0);
    float* orow = obase + (size_t)(ci * CHc) * Ec;
#pragma unroll
    for (int c = 0; c < 4; ++c)
#pragma unroll
      for (int j = 0; j < 4; ++j)
        orow[(size_t)(w * 16 + lq * 4 + j) * Ec + c * 16 + lr] = ao[c][j];
    if (ci < NCHUNK - 1) {  // restage: per-wave row-disjoint, read-before-write in-wave
      *(short8*)sws(s_x, sr, sc * 32) = pk8(pf0, pf1);
      *(short8*)sws(s_x, sr, sc * 32 + 16) = pk8(pf2, pf3);
    }
    __syncthreads();  // B3
  }
}

extern "C" void kernel_launch(void* const* d_in, const int* in_sizes, int n_in,
                              void* d_out, int out_size, void* d_ws, size_t ws_size,
                              hipStream_t stream) {
  const float* x  = (const float*)d_in[0];
  const float* Wq = (const float*)d_in[1];
  const float* Wk = (const float*)d_in[2];
  const float* Wv = (const float*)d_in[3];
  const float* Wo = (const float*)d_in[4];
  float* out = (float*)d_out;

  unsigned short* wbuf  = (unsigned short*)d_ws;                   // 24 KB used (reserve 32 KB)
  unsigned short* kvseg = (unsigned short*)((char*)d_ws + 32768);  // 8 MB bf16, P-layout

  prep_weights<<<dim3(16), dim3(256), 0, stream>>>(Wq, Wk, Wv, Wo, wbuf);
  pass1_kvseg<<<dim3(64 * (NSEG - 1)), dim3(256), 0, stream>>>(x, wbuf, kvseg);
  pass3_main<<<dim3(64 * NSEG), dim3(256), 0, stream>>>(x, wbuf, kvseg, out);
}

// Round 16
// 69.062 us; speedup vs baseline: 2.1711x; 1.1099x over previous
//
#include <hip/hip_runtime.h>
#include <cstdint>
#include <cstddef>

// Problem constants (fixed by the reference)
constexpr int Bc = 4, Tc = 4096, Ec = 1024, Hc = 16, Dc = 64, CHc = 64;
constexpr int NSEG = 16;              // segments (4 chunks serial, S in regs)
constexpr int SEGT = Tc / NSEG;       // 256 tokens
constexpr int NCHUNK = SEGT / CHc;    // 4

typedef __attribute__((ext_vector_type(8))) short short8;  // 8 bf16 MFMA A/B frag
typedef __attribute__((ext_vector_type(4))) float f32x4;   // MFMA C/D frag

// XOR-swizzled LDS tile addressing: [64][64] bf16, 128B rows, no pad (T2).
__device__ __forceinline__ unsigned short* sws(unsigned short* b, int row, int colbyte) {
  return (unsigned short*)((char*)b + (row << 7) + (colbyte ^ ((row & 7) << 4)));
}

__device__ __forceinline__ unsigned short f2bf(float f) {  // RNE (prep only)
  union { float f; unsigned int u; } v; v.f = f;
  return (unsigned short)((v.u + 0x7FFFu + ((v.u >> 16) & 1u)) >> 16);
}
// round-half-up pack of 2 fp32 -> u32(2xbf16) via v_perm_b32 (validated r7-r15).
__device__ __forceinline__ unsigned int pk2(float lo, float hi) {
  union { float f; unsigned int u; } a, b; a.f = lo; b.f = hi;
  return __builtin_amdgcn_perm(b.u + 0x8000u, a.u + 0x8000u, 0x07060302u);
}
__device__ __forceinline__ float bf2f(unsigned int u16) {  // low 16 bits = bf16
  union { unsigned int u; float f; } v; v.u = u16 << 16;
  return v.f;
}
__device__ __forceinline__ float phi_elu1(float x) {   // elu(x)+1
  return x > 0.f ? x + 1.f : __expf(x);
}
__device__ __forceinline__ short8 ld8(const unsigned short* p) {
  return *reinterpret_cast<const short8*>(p);
}
__device__ __forceinline__ short8 pk8(float4 a, float4 b) {
  union { unsigned int u[4]; short8 s; } r;
  r.u[0] = pk2(a.x, a.y); r.u[1] = pk2(a.z, a.w);
  r.u[2] = pk2(b.x, b.y); r.u[3] = pk2(b.z, b.w);
  return r.s;
}
__device__ __forceinline__ void st4(unsigned short* p, float v0, float v1, float v2, float v3) {
  uint2 t; t.x = pk2(v0, v1); t.y = pk2(v2, v3);
  *reinterpret_cast<uint2*>(p) = t;
}

#define MFMA(a, b, c) __builtin_amdgcn_mfma_f32_16x16x32_bf16((a), (b), (c), 0, 0, 0)

// ---------------- prep: wqT[e][d], wkT[e][d], wvoT[d][f] (Wvo = Wv@Wo) -> bf16 ----------------
__global__ __launch_bounds__(256) void prep_weights(
    const float* __restrict__ Wq, const float* __restrict__ Wk,
    const float* __restrict__ Wv, const float* __restrict__ Wo,
    unsigned short* __restrict__ wbuf) {
  __shared__ float s_wvT[4096];  // [g][f] = Wv[f][g]
  __shared__ float s_wo[4096];   // [g][d] = Wo[g][d]
  const int tid = threadIdx.x;
  const int i = blockIdx.x * 256 + tid;          // 0..4095
  for (int j = tid; j < 4096; j += 256) {
    s_wvT[(j & 63) * 64 + (j >> 6)] = Wv[j];
    s_wo[j] = Wo[j];
  }
  __syncthreads();
  const int r = i >> 6, c = i & 63;
  wbuf[c * 64 + r] = f2bf(Wq[i]);                // wqT[e][d] = Wq[d][e]
  wbuf[4096 + c * 64 + r] = f2bf(Wk[i]);         // wkT
  float acc = 0.f;                               // wvoT[d][f] = (Wv@Wo)[f][d];  d=r, f=c
  for (int g = 0; g < 64; ++g)
    acc += s_wvT[g * 64 + c] * s_wo[g * 64 + r];
  wbuf[8192 + i] = f2bf(acc);
}

// ---------------- pass1: per-SEGMENT KV = sum_t phi(k)^T v' -> bf16 P-layout ----------------
// grid (64 bh, 15 sg) — segment 15's KV has no consumer. 4 chunks serial; kT/vT dbuf ->
// 1 barrier/chunk; x prefetched one chunk ahead; weight frags amortized (r10, proven).
// 2D grid, NO XCD swizzle: default dispatch aligns (bh,sg) XCD placement across pass1/pass3,
// giving pass3 cross-pass L2 hits on x (r15's swizzle broke this: FETCH 38.7->63.8 MB).
__global__ __launch_bounds__(256, 3) void pass1_kvseg(
    const float* __restrict__ x, const unsigned short* __restrict__ wbuf,
    unsigned short* __restrict__ kvseg) {
  __shared__ unsigned short s_kT[2][4096];   // phi(k)^T [e][t]  (swizzled, dbuf)
  __shared__ unsigned short s_vT[2][4096];   // v'^T [d][t]      (swizzled, dbuf)
  const int tid = threadIdx.x, w = tid >> 6, lane = tid & 63, lr = lane & 15, lq = lane >> 4;
  const int bh = blockIdx.x, sg = blockIdx.y, b = bh >> 4, h = bh & 15;
  const float* xbase = x + ((size_t)b * Tc + (size_t)sg * SEGT) * Ec + h * Dc;
  const unsigned short* wkT = wbuf + 4096;
  const unsigned short* wvoT = wbuf + 8192;
  const f32x4 Z = {0.f, 0.f, 0.f, 0.f};

  short8 bwk[4][2], bwv[4][2];   // B-side weight frags (rows e / d = c*16+lr)
#pragma unroll
  for (int c = 0; c < 4; ++c)
#pragma unroll
    for (int kk = 0; kk < 2; ++kk) {
      bwk[c][kk] = ld8(wkT + (c * 16 + lr) * 64 + kk * 32 + lq * 8);
      bwv[c][kk] = ld8(wvoT + (c * 16 + lr) * 64 + kk * 32 + lq * 8);
    }

  const float* xr = xbase + (size_t)(w * 16 + lr) * Ec + lq * 8;
  float4 p0 = ((const float4*)xr)[0], p1 = ((const float4*)xr)[1];
  float4 p2 = ((const float4*)(xr + 32))[0], p3 = ((const float4*)(xr + 32))[1];

  f32x4 sacc[4] = {Z, Z, Z, Z};
#pragma unroll
  for (int ci = 0; ci < NCHUNK; ++ci) {
    unsigned short* skT = s_kT[ci & 1];
    unsigned short* svT = s_vT[ci & 1];
    short8 xa0 = pk8(p0, p1), xa1 = pk8(p2, p3);
    if (ci < NCHUNK - 1) {   // prefetch next chunk's x (hidden under this chunk)
      const float* nr = xbase + (size_t)((ci + 1) * CHc + w * 16 + lr) * Ec + lq * 8;
      p0 = ((const float4*)nr)[0]; p1 = ((const float4*)nr)[1];
      p2 = ((const float4*)(nr + 32))[0]; p3 = ((const float4*)(nr + 32))[1];
    }
    f32x4 ak[4] = {Z, Z, Z, Z}, av[4] = {Z, Z, Z, Z};
    __builtin_amdgcn_s_setprio(1);
#pragma unroll
    for (int c = 0; c < 4; ++c) {
      ak[c] = MFMA(xa0, bwk[c][0], ak[c]); ak[c] = MFMA(xa1, bwk[c][1], ak[c]);  // k[t][e]
      av[c] = MFMA(xa0, bwv[c][0], av[c]); av[c] = MFMA(xa1, bwv[c][1], av[c]);  // v'[t][d]
    }
    __builtin_amdgcn_s_setprio(0);
#pragma unroll
    for (int c = 0; c < 4; ++c) {   // transposed b64-packed stores -> [e][t] / [d][t]
      st4(sws(skT, c * 16 + lr, w * 32 + lq * 8),
          phi_elu1(ak[c][0]), phi_elu1(ak[c][1]), phi_elu1(ak[c][2]), phi_elu1(ak[c][3]));
      st4(sws(svT, c * 16 + lr, w * 32 + lq * 8), av[c][0], av[c][1], av[c][2], av[c][3]);
    }
    __syncthreads();  // one barrier per chunk (dbuf)
    short8 akt0 = ld8(sws(skT, w * 16 + lr, lq * 16));
    short8 akt1 = ld8(sws(skT, w * 16 + lr, 64 + lq * 16));
    __builtin_amdgcn_s_setprio(1);
#pragma unroll
    for (int c = 0; c < 4; ++c) {   // KV[e][d] += sum_t kT[e][t] vT[d][t]
      sacc[c] = MFMA(akt0, ld8(sws(svT, c * 16 + lr, lq * 16)), sacc[c]);
      sacc[c] = MFMA(akt1, ld8(sws(svT, c * 16 + lr, 64 + lq * 16)), sacc[c]);
    }
    __builtin_amdgcn_s_setprio(0);
  }

  // P-layout store: 4x uint2, 32B contiguous per thread, 2KB per wave
  unsigned short* dst = kvseg + ((size_t)bh * NSEG + sg) * 4096 + (w * 64 + lane) * 16;
#pragma unroll
  for (int c = 0; c < 4; ++c) {
    uint2 t; t.x = pk2(sacc[c][0], sacc[c][1]); t.y = pk2(sacc[c][2], sacc[c][3]);
    *reinterpret_cast<uint2*>(dst + c * 4) = t;
  }
}

// ---------------- pass3: r10 structure + DEFERRED out-store (below B3) ----------------
// r10 wrote out BEFORE B3; __syncthreads' vmcnt(0) drain put 16 global-store completions
// on the barrier critical path each chunk. Stores moved AFTER B3: they drain under the
// next chunk's stage A. ao lives across one barrier (+16 VGPR, still 3 waves/SIMD).
__global__ __launch_bounds__(256, 2) void pass3_main(
    const float* __restrict__ x, const unsigned short* __restrict__ wbuf,
    const unsigned short* __restrict__ kvseg, float* __restrict__ out) {
  __shared__ unsigned short s_x [4096];   // x chunk [t][d]; attn after stage B; restaged at C end
  __shared__ unsigned short s_q [4096];   // q [t][e]
  __shared__ unsigned short s_k [4096];   // k [t'][e]
  __shared__ unsigned short s_kT[4096];   // phi(k)^T [e][t]
  __shared__ unsigned short s_vT[4096];   // v'^T [d][t]
  __shared__ unsigned short s_Sb[4096];   // S^T [d][e] snapshot (pre-update)

  const int tid = threadIdx.x, w = tid >> 6, lane = tid & 63, lr = lane & 15, lq = lane >> 4;
  const int bh = blockIdx.x, sg = blockIdx.y, b = bh >> 4, h = bh & 15;
  const float* xbase = x + ((size_t)b * Tc + (size_t)sg * SEGT) * Ec + h * Dc;
  float* obase = out + ((size_t)b * Tc + (size_t)sg * SEGT) * Ec + h * Dc;
  const unsigned short* wqT = wbuf;
  const unsigned short* wkT = wbuf + 4096;
  const unsigned short* wvoT = wbuf + 8192;
  const int sr = tid >> 2, sc = tid & 3;
  const f32x4 Z = {0.f, 0.f, 0.f, 0.f};

  // S-init: exclusive prefix over predecessor segment-KVs (P-layout, coalesced, L2-resident)
  f32x4 sacc[4] = {Z, Z, Z, Z};
  {
    const unsigned short* kvb = kvseg + (size_t)bh * NSEG * 4096 + (w * 64 + lane) * 16;
    for (int sp = 0; sp < sg; ++sp) {
      const unsigned short* p = kvb + (size_t)sp * 4096;
#pragma unroll
      for (int c = 0; c < 4; ++c) {
        uint2 u = *reinterpret_cast<const uint2*>(p + c * 4);
        sacc[c][0] += bf2f(u.x & 0xFFFFu); sacc[c][1] += bf2f(u.x >> 16);
        sacc[c][2] += bf2f(u.y & 0xFFFFu); sacc[c][3] += bf2f(u.y >> 16);
      }
    }
  }

  // weight fragments in registers
  short8 awq[2], awk[2], bwk[4][2], bwv[4][2];
#pragma unroll
  for (int kk = 0; kk < 2; ++kk) {
    awq[kk] = ld8(wqT + (w * 16 + lr) * 64 + kk * 32 + lq * 8);   // A-side rows e (w-strip)
    awk[kk] = ld8(wkT + (w * 16 + lr) * 64 + kk * 32 + lq * 8);
  }
#pragma unroll
  for (int c = 0; c < 4; ++c)
#pragma unroll
    for (int kk = 0; kk < 2; ++kk) {
      bwk[c][kk] = ld8(wkT + (c * 16 + lr) * 64 + kk * 32 + lq * 8);   // B-side rows e
      bwv[c][kk] = ld8(wvoT + (c * 16 + lr) * 64 + kk * 32 + lq * 8);  // B-side rows d
    }

  {  // stage chunk0 x -> LDS (swizzled)
    const float4* xf = (const float4*)(xbase + (size_t)sr * Ec + sc * 16);
    float4 f0 = xf[0], f1 = xf[1], f2 = xf[2], f3 = xf[3];
    *(short8*)sws(s_x, sr, sc * 32) = pk8(f0, f1);
    *(short8*)sws(s_x, sr, sc * 32 + 16) = pk8(f2, f3);
  }
  __syncthreads();  // x ready

#pragma unroll
  for (int ci = 0; ci < NCHUNK; ++ci) {
    // prefetch next chunk's x into regs (consumed at end of stage C)
    float4 pf0, pf1, pf2, pf3;
    if (ci < NCHUNK - 1) {
      const float4* xf = (const float4*)(xbase + (size_t)((ci + 1) * CHc + sr) * Ec + sc * 16);
      pf0 = xf[0]; pf1 = xf[1]; pf2 = xf[2]; pf3 = xf[3];
    }

    // ---- stage A: 4 projections; all stores transposed b64-packed ----
    short8 xb[4][2];
#pragma unroll
    for (int c = 0; c < 4; ++c) {
      xb[c][0] = ld8(sws(s_x, c * 16 + lr, lq * 16));
      xb[c][1] = ld8(sws(s_x, c * 16 + lr, 64 + lq * 16));
    }
    short8 xw0 = ld8(sws(s_x, w * 16 + lr, lq * 16));        // own strip (A-side)
    short8 xw1 = ld8(sws(s_x, w * 16 + lr, 64 + lq * 16));
#pragma unroll
    for (int c = 0; c < 4; ++c)                               // S snapshot -> s_Sb[d][e]
      st4(sws(s_Sb, c * 16 + lr, w * 32 + lq * 8), sacc[c][0], sacc[c][1], sacc[c][2], sacc[c][3]);

    f32x4 aqt[4] = {Z, Z, Z, Z}, akt[4] = {Z, Z, Z, Z}, ack[4] = {Z, Z, Z, Z}, acv[4] = {Z, Z, Z, Z};
    __builtin_amdgcn_s_setprio(1);
#pragma unroll
    for (int c = 0; c < 4; ++c) {
      aqt[c] = MFMA(awq[0], xb[c][0], aqt[c]); aqt[c] = MFMA(awq[1], xb[c][1], aqt[c]);  // qT[e][t]
      akt[c] = MFMA(awk[0], xb[c][0], akt[c]); akt[c] = MFMA(awk[1], xb[c][1], akt[c]);  // kT[e][t']
      ack[c] = MFMA(xw0, bwk[c][0], ack[c]);   ack[c] = MFMA(xw1, bwk[c][1], ack[c]);    // k[t][e]
      acv[c] = MFMA(xw0, bwv[c][0], acv[c]);   acv[c] = MFMA(xw1, bwv[c][1], acv[c]);    // v'[t][d]
    }
    __builtin_amdgcn_s_setprio(0);
#pragma unroll
    for (int c = 0; c < 4; ++c) {
      const int row = c * 16 + lr, cb = w * 32 + lq * 8;
      st4(sws(s_q, row, cb), phi_elu1(aqt[c][0]), phi_elu1(aqt[c][1]), phi_elu1(aqt[c][2]), phi_elu1(aqt[c][3]));
      st4(sws(s_k, row, cb), phi_elu1(akt[c][0]), phi_elu1(akt[c][1]), phi_elu1(akt[c][2]), phi_elu1(akt[c][3]));
      st4(sws(s_kT, row, cb), phi_elu1(ack[c][0]), phi_elu1(ack[c][1]), phi_elu1(ack[c][2]), phi_elu1(ack[c][3]));
      st4(sws(s_vT, row, cb), acv[c][0], acv[c][1], acv[c][2], acv[c][3]);
    }
    __syncthreads();  // B1

    // ---- stage B: attnT = k q^T (masked); o_inter = q@S; S += kT@v' ----
    short8 a_q0 = ld8(sws(s_q, w * 16 + lr, lq * 16));
    short8 a_q1 = ld8(sws(s_q, w * 16 + lr, 64 + lq * 16));
    short8 a_k0 = ld8(sws(s_k, w * 16 + lr, lq * 16));
    short8 a_k1 = ld8(sws(s_k, w * 16 + lr, 64 + lq * 16));
    short8 a_t0 = ld8(sws(s_kT, w * 16 + lr, lq * 16));
    short8 a_t1 = ld8(sws(s_kT, w * 16 + lr, 64 + lq * 16));
    f32x4 aat[4] = {Z, Z, Z, Z}, ao[4] = {Z, Z, Z, Z};
    __builtin_amdgcn_s_setprio(1);
#pragma unroll
    for (int c = 0; c < 4; ++c) {
      const int row = c * 16 + lr;
      aat[c]  = MFMA(a_k0, ld8(sws(s_q, row, lq * 16)), aat[c]);
      aat[c]  = MFMA(a_k1, ld8(sws(s_q, row, 64 + lq * 16)), aat[c]);
      ao[c]   = MFMA(a_q0, ld8(sws(s_Sb, row, lq * 16)), ao[c]);
      ao[c]   = MFMA(a_q1, ld8(sws(s_Sb, row, 64 + lq * 16)), ao[c]);
      sacc[c] = MFMA(a_t0, ld8(sws(s_vT, row, lq * 16)), sacc[c]);
      sacc[c] = MFMA(a_t1, ld8(sws(s_vT, row, 64 + lq * 16)), sacc[c]);
    }
    __builtin_amdgcn_s_setprio(0);
    // masked attnT (acc row t'=w16+lq*4+j, col t=c*16+lr) -> store attn[t][t'] into s_x
#pragma unroll
    for (int c = 0; c < 4; ++c) {
      int t = c * 16 + lr, tp = w * 16 + lq * 4;
      float m0 = (tp + 0 <= t) ? aat[c][0] : 0.f;
      float m1 = (tp + 1 <= t) ? aat[c][1] : 0.f;
      float m2 = (tp + 2 <= t) ? aat[c][2] : 0.f;
      float m3 = (tp + 3 <= t) ? aat[c][3] : 0.f;
      st4(sws(s_x, t, tp * 2), m0, m1, m2, m3);
    }
    __syncthreads();  // B2

    // ---- stage C: o += attn@v'; restage next x; BARRIER; then write out (deferred) ----
    short8 a_a0 = ld8(sws(s_x, w * 16 + lr, lq * 16));
    short8 a_a1 = ld8(sws(s_x, w * 16 + lr, 64 + lq * 16));
    __builtin_amdgcn_s_setprio(1);
#pragma unroll
    for (int c = 0; c < 4; ++c) {
      const int row = c * 16 + lr;
      ao[c] = MFMA(a_a0, ld8(sws(s_vT, row, lq * 16)), ao[c]);
      ao[c] = MFMA(a_a1, ld8(sws(s_vT, row, 64 + lq * 16)), ao[c]);
    }
    __builtin_amdgcn_s_setprio(0);
    if (ci < NCHUNK - 1) {  // restage: per-wave row-disjoint, read-before-write in-wave
      *(short8*)sws(s_x, sr, sc * 32) = pk8(pf0, pf1);
      *(short8*)sws(s_x, sr, sc * 32 + 16) = pk8(pf2, pf3);
    }
    __syncthreads();  // B3 (no global stores in flight -> drain is LDS-only)

    // deferred out-store: issues after the barrier, completes under next chunk's stage A
    float* orow = obase + (size_t)(ci * CHc) * Ec;
#pragma unroll
    for (int c = 0; c < 4; ++c)
#pragma unroll
      for (int j = 0; j < 4; ++j)
        orow[(size_t)(w * 16 + lq * 4 + j) * Ec + c * 16 + lr] = ao[c][j];
  }
}

extern "C" void kernel_launch(void* const* d_in, const int* in_sizes, int n_in,
                              void* d_out, int out_size, void* d_ws, size_t ws_size,
                              hipStream_t stream) {
  const float* x  = (const float*)d_in[0];
  const float* Wq = (const float*)d_in[1];
  const float* Wk = (const float*)d_in[2];
  const float* Wv = (const float*)d_in[3];
  const float* Wo = (const float*)d_in[4];
  float* out = (float*)d_out;

  unsigned short* wbuf  = (unsigned short*)d_ws;                   // 24 KB used (reserve 32 KB)
  unsigned short* kvseg = (unsigned short*)((char*)d_ws + 32768);  // 8 MB bf16, P-layout

  prep_weights<<<dim3(16), dim3(256), 0, stream>>>(Wq, Wk, Wv, Wo, wbuf);
  pass1_kvseg<<<dim3(64, NSEG - 1), dim3(256), 0, stream>>>(x, wbuf, kvseg);
  pass3_main<<<dim3(64, NSEG), dim3(256), 0, stream>>>(x, wbuf, kvseg, out);
}

// Round 17
// 69.058 us; speedup vs baseline: 2.1713x; 1.0001x over previous
//
#include <hip/hip_runtime.h>
#include <cstdint>
#include <cstddef>

// Problem constants (fixed by the reference)
constexpr int Bc = 4, Tc = 4096, Ec = 1024, Hc = 16, Dc = 64, CHc = 64;
constexpr int NSEG = 16;              // segments (4 chunks serial, S in regs)
constexpr int SEGT = Tc / NSEG;       // 256 tokens
constexpr int NCHUNK = SEGT / CHc;    // 4

typedef __attribute__((ext_vector_type(8))) short short8;  // 8 bf16 MFMA A/B frag
typedef __attribute__((ext_vector_type(4))) float f32x4;   // MFMA C/D frag

// XOR-swizzled LDS tile addressing: [64][64] bf16, 128B rows, no pad (T2).
__device__ __forceinline__ unsigned short* sws(unsigned short* b, int row, int colbyte) {
  return (unsigned short*)((char*)b + (row << 7) + (colbyte ^ ((row & 7) << 4)));
}

__device__ __forceinline__ unsigned short f2bf(float f) {  // RNE (prep only)
  union { float f; unsigned int u; } v; v.f = f;
  return (unsigned short)((v.u + 0x7FFFu + ((v.u >> 16) & 1u)) >> 16);
}
// round-half-up pack of 2 fp32 -> u32(2xbf16) via v_perm_b32 (validated r7-r15).
__device__ __forceinline__ unsigned int pk2(float lo, float hi) {
  union { float f; unsigned int u; } a, b; a.f = lo; b.f = hi;
  return __builtin_amdgcn_perm(b.u + 0x8000u, a.u + 0x8000u, 0x07060302u);
}
__device__ __forceinline__ float bf2f(unsigned int u16) {  // low 16 bits = bf16
  union { unsigned int u; float f; } v; v.u = u16 << 16;
  return v.f;
}
__device__ __forceinline__ float phi_elu1(float x) {   // elu(x)+1
  return x > 0.f ? x + 1.f : __expf(x);
}
__device__ __forceinline__ short8 ld8(const unsigned short* p) {
  return *reinterpret_cast<const short8*>(p);
}
__device__ __forceinline__ short8 pk8(float4 a, float4 b) {
  union { unsigned int u[4]; short8 s; } r;
  r.u[0] = pk2(a.x, a.y); r.u[1] = pk2(a.z, a.w);
  r.u[2] = pk2(b.x, b.y); r.u[3] = pk2(b.z, b.w);
  return r.s;
}
__device__ __forceinline__ void st4(unsigned short* p, float v0, float v1, float v2, float v3) {
  uint2 t; t.x = pk2(v0, v1); t.y = pk2(v2, v3);
  *reinterpret_cast<uint2*>(p) = t;
}

#define MFMA(a, b, c) __builtin_amdgcn_mfma_f32_16x16x32_bf16((a), (b), (c), 0, 0, 0)

// ---------------- prep: wqT[e][d], wkT[e][d], wvoT[d][f] (Wvo = Wv@Wo) -> bf16 ----------------
__global__ __launch_bounds__(256) void prep_weights(
    const float* __restrict__ Wq, const float* __restrict__ Wk,
    const float* __restrict__ Wv, const float* __restrict__ Wo,
    unsigned short* __restrict__ wbuf) {
  __shared__ float s_wvT[4096];  // [g][f] = Wv[f][g]
  __shared__ float s_wo[4096];   // [g][d] = Wo[g][d]
  const int tid = threadIdx.x;
  const int i = blockIdx.x * 256 + tid;          // 0..4095
  for (int j = tid; j < 4096; j += 256) {
    s_wvT[(j & 63) * 64 + (j >> 6)] = Wv[j];
    s_wo[j] = Wo[j];
  }
  __syncthreads();
  const int r = i >> 6, c = i & 63;
  wbuf[c * 64 + r] = f2bf(Wq[i]);                // wqT[e][d] = Wq[d][e]
  wbuf[4096 + c * 64 + r] = f2bf(Wk[i]);         // wkT
  float acc = 0.f;                               // wvoT[d][f] = (Wv@Wo)[f][d];  d=r, f=c
  for (int g = 0; g < 64; ++g)
    acc += s_wvT[g * 64 + c] * s_wo[g * 64 + r];
  wbuf[8192 + i] = f2bf(acc);
}

// ---------------- pass1: per-SEGMENT KV = sum_t phi(k)^T v' -> bf16 P-layout ----------------
// grid (64 bh, 15 sg) — segment 15's KV has no consumer. 4 chunks serial; kT/vT dbuf ->
// 1 barrier/chunk; x prefetched one chunk ahead; weight frags amortized (r10, proven).
// 2D grid, NO XCD swizzle: default dispatch aligns (bh,sg) XCD placement across pass1/pass3,
// giving pass3 cross-pass L2 hits on x (r15's swizzle broke this: FETCH 38.7->63.8 MB).
__global__ __launch_bounds__(256, 3) void pass1_kvseg(
    const float* __restrict__ x, const unsigned short* __restrict__ wbuf,
    unsigned short* __restrict__ kvseg) {
  __shared__ unsigned short s_kT[2][4096];   // phi(k)^T [e][t]  (swizzled, dbuf)
  __shared__ unsigned short s_vT[2][4096];   // v'^T [d][t]      (swizzled, dbuf)
  const int tid = threadIdx.x, w = tid >> 6, lane = tid & 63, lr = lane & 15, lq = lane >> 4;
  const int bh = blockIdx.x, sg = blockIdx.y, b = bh >> 4, h = bh & 15;
  const float* xbase = x + ((size_t)b * Tc + (size_t)sg * SEGT) * Ec + h * Dc;
  const unsigned short* wkT = wbuf + 4096;
  const unsigned short* wvoT = wbuf + 8192;
  const f32x4 Z = {0.f, 0.f, 0.f, 0.f};

  short8 bwk[4][2], bwv[4][2];   // B-side weight frags (rows e / d = c*16+lr)
#pragma unroll
  for (int c = 0; c < 4; ++c)
#pragma unroll
    for (int kk = 0; kk < 2; ++kk) {
      bwk[c][kk] = ld8(wkT + (c * 16 + lr) * 64 + kk * 32 + lq * 8);
      bwv[c][kk] = ld8(wvoT + (c * 16 + lr) * 64 + kk * 32 + lq * 8);
    }

  const float* xr = xbase + (size_t)(w * 16 + lr) * Ec + lq * 8;
  float4 p0 = ((const float4*)xr)[0], p1 = ((const float4*)xr)[1];
  float4 p2 = ((const float4*)(xr + 32))[0], p3 = ((const float4*)(xr + 32))[1];

  f32x4 sacc[4] = {Z, Z, Z, Z};
#pragma unroll
  for (int ci = 0; ci < NCHUNK; ++ci) {
    unsigned short* skT = s_kT[ci & 1];
    unsigned short* svT = s_vT[ci & 1];
    short8 xa0 = pk8(p0, p1), xa1 = pk8(p2, p3);
    if (ci < NCHUNK - 1) {   // prefetch next chunk's x (hidden under this chunk)
      const float* nr = xbase + (size_t)((ci + 1) * CHc + w * 16 + lr) * Ec + lq * 8;
      p0 = ((const float4*)nr)[0]; p1 = ((const float4*)nr)[1];
      p2 = ((const float4*)(nr + 32))[0]; p3 = ((const float4*)(nr + 32))[1];
    }
    f32x4 ak[4] = {Z, Z, Z, Z}, av[4] = {Z, Z, Z, Z};
    __builtin_amdgcn_s_setprio(1);
#pragma unroll
    for (int c = 0; c < 4; ++c) {
      ak[c] = MFMA(xa0, bwk[c][0], ak[c]); ak[c] = MFMA(xa1, bwk[c][1], ak[c]);  // k[t][e]
      av[c] = MFMA(xa0, bwv[c][0], av[c]); av[c] = MFMA(xa1, bwv[c][1], av[c]);  // v'[t][d]
    }
    __builtin_amdgcn_s_setprio(0);
#pragma unroll
    for (int c = 0; c < 4; ++c) {   // transposed b64-packed stores -> [e][t] / [d][t]
      st4(sws(skT, c * 16 + lr, w * 32 + lq * 8),
          phi_elu1(ak[c][0]), phi_elu1(ak[c][1]), phi_elu1(ak[c][2]), phi_elu1(ak[c][3]));
      st4(sws(svT, c * 16 + lr, w * 32 + lq * 8), av[c][0], av[c][1], av[c][2], av[c][3]);
    }
    __syncthreads();  // one barrier per chunk (dbuf)
    short8 akt0 = ld8(sws(skT, w * 16 + lr, lq * 16));
    short8 akt1 = ld8(sws(skT, w * 16 + lr, 64 + lq * 16));
    __builtin_amdgcn_s_setprio(1);
#pragma unroll
    for (int c = 0; c < 4; ++c) {   // KV[e][d] += sum_t kT[e][t] vT[d][t]
      sacc[c] = MFMA(akt0, ld8(sws(svT, c * 16 + lr, lq * 16)), sacc[c]);
      sacc[c] = MFMA(akt1, ld8(sws(svT, c * 16 + lr, 64 + lq * 16)), sacc[c]);
    }
    __builtin_amdgcn_s_setprio(0);
  }

  // P-layout store: 4x uint2, 32B contiguous per thread, 2KB per wave
  unsigned short* dst = kvseg + ((size_t)bh * NSEG + sg) * 4096 + (w * 64 + lane) * 16;
#pragma unroll
  for (int c = 0; c < 4; ++c) {
    uint2 t; t.x = pk2(sacc[c][0], sacc[c][1]); t.y = pk2(sacc[c][2], sacc[c][3]);
    *reinterpret_cast<uint2*>(dst + c * 4) = t;
  }
}

// ---------------- pass3: r10 structure + DEFERRED out-store (below B3) ----------------
// r10 wrote out BEFORE B3; __syncthreads' vmcnt(0) drain put 16 global-store completions
// on the barrier critical path each chunk. Stores moved AFTER B3: they drain under the
// next chunk's stage A. ao lives across one barrier (+16 VGPR, still 3 waves/SIMD).
__global__ __launch_bounds__(256, 2) void pass3_main(
    const float* __restrict__ x, const unsigned short* __restrict__ wbuf,
    const unsigned short* __restrict__ kvseg, float* __restrict__ out) {
  __shared__ unsigned short s_x [4096];   // x chunk [t][d]; attn after stage B; restaged at C end
  __shared__ unsigned short s_q [4096];   // q [t][e]
  __shared__ unsigned short s_k [4096];   // k [t'][e]
  __shared__ unsigned short s_kT[4096];   // phi(k)^T [e][t]
  __shared__ unsigned short s_vT[4096];   // v'^T [d][t]
  __shared__ unsigned short s_Sb[4096];   // S^T [d][e] snapshot (pre-update)

  const int tid = threadIdx.x, w = tid >> 6, lane = tid & 63, lr = lane & 15, lq = lane >> 4;
  const int bh = blockIdx.x, sg = blockIdx.y, b = bh >> 4, h = bh & 15;
  const float* xbase = x + ((size_t)b * Tc + (size_t)sg * SEGT) * Ec + h * Dc;
  float* obase = out + ((size_t)b * Tc + (size_t)sg * SEGT) * Ec + h * Dc;
  const unsigned short* wqT = wbuf;
  const unsigned short* wkT = wbuf + 4096;
  const unsigned short* wvoT = wbuf + 8192;
  const int sr = tid >> 2, sc = tid & 3;
  const f32x4 Z = {0.f, 0.f, 0.f, 0.f};

  // S-init: exclusive prefix over predecessor segment-KVs (P-layout, coalesced, L2-resident)
  f32x4 sacc[4] = {Z, Z, Z, Z};
  {
    const unsigned short* kvb = kvseg + (size_t)bh * NSEG * 4096 + (w * 64 + lane) * 16;
    for (int sp = 0; sp < sg; ++sp) {
      const unsigned short* p = kvb + (size_t)sp * 4096;
#pragma unroll
      for (int c = 0; c < 4; ++c) {
        uint2 u = *reinterpret_cast<const uint2*>(p + c * 4);
        sacc[c][0] += bf2f(u.x & 0xFFFFu); sacc[c][1] += bf2f(u.x >> 16);
        sacc[c][2] += bf2f(u.y & 0xFFFFu); sacc[c][3] += bf2f(u.y >> 16);
      }
    }
  }

  // weight fragments in registers
  short8 awq[2], awk[2], bwk[4][2], bwv[4][2];
#pragma unroll
  for (int kk = 0; kk < 2; ++kk) {
    awq[kk] = ld8(wqT + (w * 16 + lr) * 64 + kk * 32 + lq * 8);   // A-side rows e (w-strip)
    awk[kk] = ld8(wkT + (w * 16 + lr) * 64 + kk * 32 + lq * 8);
  }
#pragma unroll
  for (int c = 0; c < 4; ++c)
#pragma unroll
    for (int kk = 0; kk < 2; ++kk) {
      bwk[c][kk] = ld8(wkT + (c * 16 + lr) * 64 + kk * 32 + lq * 8);   // B-side rows e
      bwv[c][kk] = ld8(wvoT + (c * 16 + lr) * 64 + kk * 32 + lq * 8);  // B-side rows d
    }

  {  // stage chunk0 x -> LDS (swizzled)
    const float4* xf = (const float4*)(xbase + (size_t)sr * Ec + sc * 16);
    float4 f0 = xf[0], f1 = xf[1], f2 = xf[2], f3 = xf[3];
    *(short8*)sws(s_x, sr, sc * 32) = pk8(f0, f1);
    *(short8*)sws(s_x, sr, sc * 32 + 16) = pk8(f2, f3);
  }
  __syncthreads();  // x ready

#pragma unroll
  for (int ci = 0; ci < NCHUNK; ++ci) {
    // prefetch next chunk's x into regs (consumed at end of stage C)
    float4 pf0, pf1, pf2, pf3;
    if (ci < NCHUNK - 1) {
      const float4* xf = (const float4*)(xbase + (size_t)((ci + 1) * CHc + sr) * Ec + sc * 16);
      pf0 = xf[0]; pf1 = xf[1]; pf2 = xf[2]; pf3 = xf[3];
    }

    // ---- stage A: 4 projections; all stores transposed b64-packed ----
    short8 xb[4][2];
#pragma unroll
    for (int c = 0; c < 4; ++c) {
      xb[c][0] = ld8(sws(s_x, c * 16 + lr, lq * 16));
      xb[c][1] = ld8(sws(s_x, c * 16 + lr, 64 + lq * 16));
    }
    short8 xw0 = ld8(sws(s_x, w * 16 + lr, lq * 16));        // own strip (A-side)
    short8 xw1 = ld8(sws(s_x, w * 16 + lr, 64 + lq * 16));
#pragma unroll
    for (int c = 0; c < 4; ++c)                               // S snapshot -> s_Sb[d][e]
      st4(sws(s_Sb, c * 16 + lr, w * 32 + lq * 8), sacc[c][0], sacc[c][1], sacc[c][2], sacc[c][3]);

    f32x4 aqt[4] = {Z, Z, Z, Z}, akt[4] = {Z, Z, Z, Z}, ack[4] = {Z, Z, Z, Z}, acv[4] = {Z, Z, Z, Z};
    __builtin_amdgcn_s_setprio(1);
#pragma unroll
    for (int c = 0; c < 4; ++c) {
      aqt[c] = MFMA(awq[0], xb[c][0], aqt[c]); aqt[c] = MFMA(awq[1], xb[c][1], aqt[c]);  // qT[e][t]
      akt[c] = MFMA(awk[0], xb[c][0], akt[c]); akt[c] = MFMA(awk[1], xb[c][1], akt[c]);  // kT[e][t']
      ack[c] = MFMA(xw0, bwk[c][0], ack[c]);   ack[c] = MFMA(xw1, bwk[c][1], ack[c]);    // k[t][e]
      acv[c] = MFMA(xw0, bwv[c][0], acv[c]);   acv[c] = MFMA(xw1, bwv[c][1], acv[c]);    // v'[t][d]
    }
    __builtin_amdgcn_s_setprio(0);
#pragma unroll
    for (int c = 0; c < 4; ++c) {
      const int row = c * 16 + lr, cb = w * 32 + lq * 8;
      st4(sws(s_q, row, cb), phi_elu1(aqt[c][0]), phi_elu1(aqt[c][1]), phi_elu1(aqt[c][2]), phi_elu1(aqt[c][3]));
      st4(sws(s_k, row, cb), phi_elu1(akt[c][0]), phi_elu1(akt[c][1]), phi_elu1(akt[c][2]), phi_elu1(akt[c][3]));
      st4(sws(s_kT, row, cb), phi_elu1(ack[c][0]), phi_elu1(ack[c][1]), phi_elu1(ack[c][2]), phi_elu1(ack[c][3]));
      st4(sws(s_vT, row, cb), acv[c][0], acv[c][1], acv[c][2], acv[c][3]);
    }
    __syncthreads();  // B1

    // ---- stage B: attnT = k q^T (masked); o_inter = q@S; S += kT@v' ----
    short8 a_q0 = ld8(sws(s_q, w * 16 + lr, lq * 16));
    short8 a_q1 = ld8(sws(s_q, w * 16 + lr, 64 + lq * 16));
    short8 a_k0 = ld8(sws(s_k, w * 16 + lr, lq * 16));
    short8 a_k1 = ld8(sws(s_k, w * 16 + lr, 64 + lq * 16));
    short8 a_t0 = ld8(sws(s_kT, w * 16 + lr, lq * 16));
    short8 a_t1 = ld8(sws(s_kT, w * 16 + lr, 64 + lq * 16));
    f32x4 aat[4] = {Z, Z, Z, Z}, ao[4] = {Z, Z, Z, Z};
    __builtin_amdgcn_s_setprio(1);
#pragma unroll
    for (int c = 0; c < 4; ++c) {
      const int row = c * 16 + lr;
      aat[c]  = MFMA(a_k0, ld8(sws(s_q, row, lq * 16)), aat[c]);
      aat[c]  = MFMA(a_k1, ld8(sws(s_q, row, 64 + lq * 16)), aat[c]);
      ao[c]   = MFMA(a_q0, ld8(sws(s_Sb, row, lq * 16)), ao[c]);
      ao[c]   = MFMA(a_q1, ld8(sws(s_Sb, row, 64 + lq * 16)), ao[c]);
      sacc[c] = MFMA(a_t0, ld8(sws(s_vT, row, lq * 16)), sacc[c]);
      sacc[c] = MFMA(a_t1, ld8(sws(s_vT, row, 64 + lq * 16)), sacc[c]);
    }
    __builtin_amdgcn_s_setprio(0);
    // masked attnT (acc row t'=w16+lq*4+j, col t=c*16+lr) -> store attn[t][t'] into s_x
#pragma unroll
    for (int c = 0; c < 4; ++c) {
      int t = c * 16 + lr, tp = w * 16 + lq * 4;
      float m0 = (tp + 0 <= t) ? aat[c][0] : 0.f;
      float m1 = (tp + 1 <= t) ? aat[c][1] : 0.f;
      float m2 = (tp + 2 <= t) ? aat[c][2] : 0.f;
      float m3 = (tp + 3 <= t) ? aat[c][3] : 0.f;
      st4(sws(s_x, t, tp * 2), m0, m1, m2, m3);
    }
    __syncthreads();  // B2

    // ---- stage C: o += attn@v'; restage next x; BARRIER; then write out (deferred) ----
    short8 a_a0 = ld8(sws(s_x, w * 16 + lr, lq * 16));
    short8 a_a1 = ld8(sws(s_x, w * 16 + lr, 64 + lq * 16));
    __builtin_amdgcn_s_setprio(1);
#pragma unroll
    for (int c = 0; c < 4; ++c) {
      const int row = c * 16 + lr;
      ao[c] = MFMA(a_a0, ld8(sws(s_vT, row, lq * 16)), ao[c]);
      ao[c] = MFMA(a_a1, ld8(sws(s_vT, row, 64 + lq * 16)), ao[c]);
    }
    __builtin_amdgcn_s_setprio(0);
    if (ci < NCHUNK - 1) {  // restage: per-wave row-disjoint, read-before-write in-wave
      *(short8*)sws(s_x, sr, sc * 32) = pk8(pf0, pf1);
      *(short8*)sws(s_x, sr, sc * 32 + 16) = pk8(pf2, pf3);
    }
    __syncthreads();  // B3 (no global stores in flight -> drain is LDS-only)

    // deferred out-store: issues after the barrier, completes under next chunk's stage A
    float* orow = obase + (size_t)(ci * CHc) * Ec;
#pragma unroll
    for (int c = 0; c < 4; ++c)
#pragma unroll
      for (int j = 0; j < 4; ++j)
        orow[(size_t)(w * 16 + lq * 4 + j) * Ec + c * 16 + lr] = ao[c][j];
  }
}

extern "C" void kernel_launch(void* const* d_in, const int* in_sizes, int n_in,
                              void* d_out, int out_size, void* d_ws, size_t ws_size,
                              hipStream_t stream) {
  const float* x  = (const float*)d_in[0];
  const float* Wq = (const float*)d_in[1];
  const float* Wk = (const float*)d_in[2];
  const float* Wv = (const float*)d_in[3];
  const float* Wo = (const float*)d_in[4];
  float* out = (float*)d_out;

  unsigned short* wbuf  = (unsigned short*)d_ws;                   // 24 KB used (reserve 32 KB)
  unsigned short* kvseg = (unsigned short*)((char*)d_ws + 32768);  // 8 MB bf16, P-layout

  prep_weights<<<dim3(16), dim3(256), 0, stream>>>(Wq, Wk, Wv, Wo, wbuf);
  pass1_kvseg<<<dim3(64, NSEG - 1), dim3(256), 0, stream>>>(x, wbuf, kvseg);
  pass3_main<<<dim3(64, NSEG), dim3(256), 0, stream>>>(x, wbuf, kvseg, out);
}

// Round 18
// 67.433 us; speedup vs baseline: 2.2236x; 1.0241x over previous
//
#include <hip/hip_runtime.h>
#include <cstdint>
#include <cstddef>

// Problem constants (fixed by the reference)
constexpr int Bc = 4, Tc = 4096, Ec = 1024, Hc = 16, Dc = 64, CHc = 64;
constexpr int NSEG = 16;              // segments (4 chunks serial, S in regs)
constexpr int SEGT = Tc / NSEG;       // 256 tokens
constexpr int NCHUNK = SEGT / CHc;    // 4

typedef __attribute__((ext_vector_type(8))) short short8;  // 8 bf16 MFMA A/B frag
typedef __attribute__((ext_vector_type(4))) float f32x4;   // MFMA C/D frag

// XOR-swizzled LDS tile addressing: [64][64] bf16, 128B rows, no pad (T2).
__device__ __forceinline__ unsigned short* sws(unsigned short* b, int row, int colbyte) {
  return (unsigned short*)((char*)b + (row << 7) + (colbyte ^ ((row & 7) << 4)));
}

__device__ __forceinline__ unsigned short f2bf(float f) {  // RNE (prep only)
  union { float f; unsigned int u; } v; v.f = f;
  return (unsigned short)((v.u + 0x7FFFu + ((v.u >> 16) & 1u)) >> 16);
}
// round-half-up pack of 2 fp32 -> u32(2xbf16) via v_perm_b32 (validated r7-r17).
__device__ __forceinline__ unsigned int pk2(float lo, float hi) {
  union { float f; unsigned int u; } a, b; a.f = lo; b.f = hi;
  return __builtin_amdgcn_perm(b.u + 0x8000u, a.u + 0x8000u, 0x07060302u);
}
__device__ __forceinline__ float bf2f(unsigned int u16) {  // low 16 bits = bf16
  union { unsigned int u; float f; } v; v.u = u16 << 16;
  return v.f;
}
__device__ __forceinline__ float phi_elu1(float x) {   // elu(x)+1
  return x > 0.f ? x + 1.f : __expf(x);
}
__device__ __forceinline__ short8 ld8(const unsigned short* p) {
  return *reinterpret_cast<const short8*>(p);
}
__device__ __forceinline__ short8 pk8(float4 a, float4 b) {
  union { unsigned int u[4]; short8 s; } r;
  r.u[0] = pk2(a.x, a.y); r.u[1] = pk2(a.z, a.w);
  r.u[2] = pk2(b.x, b.y); r.u[3] = pk2(b.z, b.w);
  return r.s;
}
__device__ __forceinline__ void st4(unsigned short* p, float v0, float v1, float v2, float v3) {
  uint2 t; t.x = pk2(v0, v1); t.y = pk2(v2, v3);
  *reinterpret_cast<uint2*>(p) = t;
}

#define MFMA(a, b, c) __builtin_amdgcn_mfma_f32_16x16x32_bf16((a), (b), (c), 0, 0, 0)

// ---------------- prep: wqT[e][d], wkT[e][d], wvoT[d][f] (Wvo = Wv@Wo) -> bf16 ----------------
__global__ __launch_bounds__(256) void prep_weights(
    const float* __restrict__ Wq, const float* __restrict__ Wk,
    const float* __restrict__ Wv, const float* __restrict__ Wo,
    unsigned short* __restrict__ wbuf) {
  __shared__ float s_wvT[4096];  // [g][f] = Wv[f][g]
  __shared__ float s_wo[4096];   // [g][d] = Wo[g][d]
  const int tid = threadIdx.x;
  const int i = blockIdx.x * 256 + tid;          // 0..4095
  for (int j = tid; j < 4096; j += 256) {
    s_wvT[(j & 63) * 64 + (j >> 6)] = Wv[j];
    s_wo[j] = Wo[j];
  }
  __syncthreads();
  const int r = i >> 6, c = i & 63;
  wbuf[c * 64 + r] = f2bf(Wq[i]);                // wqT[e][d] = Wq[d][e]
  wbuf[4096 + c * 64 + r] = f2bf(Wk[i]);         // wkT
  float acc = 0.f;                               // wvoT[d][f] = (Wv@Wo)[f][d];  d=r, f=c
  for (int g = 0; g < 64; ++g)
    acc += s_wvT[g * 64 + c] * s_wo[g * 64 + r];
  wbuf[8192 + i] = f2bf(acc);
}

// ---------------- pass1: per-SEGMENT KV = sum_t phi(k)^T v' -> bf16 P-layout ----------------
// grid (64 bh, 15 sg) — segment 15's KV has no consumer (isolated win, r16/17).
// 4 chunks serial; kT/vT dbuf -> 1 barrier/chunk; x prefetched one chunk ahead;
// weight frags amortized. 2D grid, NO XCD swizzle (r15: swizzle broke cross-pass L2 reuse).
__global__ __launch_bounds__(256, 3) void pass1_kvseg(
    const float* __restrict__ x, const unsigned short* __restrict__ wbuf,
    unsigned short* __restrict__ kvseg) {
  __shared__ unsigned short s_kT[2][4096];   // phi(k)^T [e][t]  (swizzled, dbuf)
  __shared__ unsigned short s_vT[2][4096];   // v'^T [d][t]      (swizzled, dbuf)
  const int tid = threadIdx.x, w = tid >> 6, lane = tid & 63, lr = lane & 15, lq = lane >> 4;
  const int bh = blockIdx.x, sg = blockIdx.y, b = bh >> 4, h = bh & 15;
  const float* xbase = x + ((size_t)b * Tc + (size_t)sg * SEGT) * Ec + h * Dc;
  const unsigned short* wkT = wbuf + 4096;
  const unsigned short* wvoT = wbuf + 8192;
  const f32x4 Z = {0.f, 0.f, 0.f, 0.f};

  short8 bwk[4][2], bwv[4][2];   // B-side weight frags (rows e / d = c*16+lr)
#pragma unroll
  for (int c = 0; c < 4; ++c)
#pragma unroll
    for (int kk = 0; kk < 2; ++kk) {
      bwk[c][kk] = ld8(wkT + (c * 16 + lr) * 64 + kk * 32 + lq * 8);
      bwv[c][kk] = ld8(wvoT + (c * 16 + lr) * 64 + kk * 32 + lq * 8);
    }

  const float* xr = xbase + (size_t)(w * 16 + lr) * Ec + lq * 8;
  float4 p0 = ((const float4*)xr)[0], p1 = ((const float4*)xr)[1];
  float4 p2 = ((const float4*)(xr + 32))[0], p3 = ((const float4*)(xr + 32))[1];

  f32x4 sacc[4] = {Z, Z, Z, Z};
#pragma unroll
  for (int ci = 0; ci < NCHUNK; ++ci) {
    unsigned short* skT = s_kT[ci & 1];
    unsigned short* svT = s_vT[ci & 1];
    short8 xa0 = pk8(p0, p1), xa1 = pk8(p2, p3);
    if (ci < NCHUNK - 1) {   // prefetch next chunk's x (hidden under this chunk)
      const float* nr = xbase + (size_t)((ci + 1) * CHc + w * 16 + lr) * Ec + lq * 8;
      p0 = ((const float4*)nr)[0]; p1 = ((const float4*)nr)[1];
      p2 = ((const float4*)(nr + 32))[0]; p3 = ((const float4*)(nr + 32))[1];
    }
    f32x4 ak[4] = {Z, Z, Z, Z}, av[4] = {Z, Z, Z, Z};
    __builtin_amdgcn_s_setprio(1);
#pragma unroll
    for (int c = 0; c < 4; ++c) {
      ak[c] = MFMA(xa0, bwk[c][0], ak[c]); ak[c] = MFMA(xa1, bwk[c][1], ak[c]);  // k[t][e]
      av[c] = MFMA(xa0, bwv[c][0], av[c]); av[c] = MFMA(xa1, bwv[c][1], av[c]);  // v'[t][d]
    }
    __builtin_amdgcn_s_setprio(0);
#pragma unroll
    for (int c = 0; c < 4; ++c) {   // transposed b64-packed stores -> [e][t] / [d][t]
      st4(sws(skT, c * 16 + lr, w * 32 + lq * 8),
          phi_elu1(ak[c][0]), phi_elu1(ak[c][1]), phi_elu1(ak[c][2]), phi_elu1(ak[c][3]));
      st4(sws(svT, c * 16 + lr, w * 32 + lq * 8), av[c][0], av[c][1], av[c][2], av[c][3]);
    }
    __syncthreads();  // one barrier per chunk (dbuf)
    short8 akt0 = ld8(sws(skT, w * 16 + lr, lq * 16));
    short8 akt1 = ld8(sws(skT, w * 16 + lr, 64 + lq * 16));
    __builtin_amdgcn_s_setprio(1);
#pragma unroll
    for (int c = 0; c < 4; ++c) {   // KV[e][d] += sum_t kT[e][t] vT[d][t]
      sacc[c] = MFMA(akt0, ld8(sws(svT, c * 16 + lr, lq * 16)), sacc[c]);
      sacc[c] = MFMA(akt1, ld8(sws(svT, c * 16 + lr, 64 + lq * 16)), sacc[c]);
    }
    __builtin_amdgcn_s_setprio(0);
  }

  // P-layout store: 4x uint2, 32B contiguous per thread, 2KB per wave
  unsigned short* dst = kvseg + ((size_t)bh * NSEG + sg) * 4096 + (w * 64 + lane) * 16;
#pragma unroll
  for (int c = 0; c < 4; ++c) {
    uint2 t; t.x = pk2(sacc[c][0], sacc[c][1]); t.y = pk2(sacc[c][2], sacc[c][3]);
    *reinterpret_cast<uint2*>(dst + c * 4) = t;
  }
}

// ---------------- pass3: r10 structure VERBATIM (proven best: 46.3us) ----------------
// 48KB LDS, 4 waves, (256,2), 3 barriers/chunk, out-store BEFORE B3. Beat: 8-wave (+5us),
// merged-BC (+3), 5-tile (+100 spill), (256,3) (+60 spill), fused (+240), XCD swz (+9),
// deferred store (+3). Latency-bound local optimum for this decomposition.
__global__ __launch_bounds__(256, 2) void pass3_main(
    const float* __restrict__ x, const unsigned short* __restrict__ wbuf,
    const unsigned short* __restrict__ kvseg, float* __restrict__ out) {
  __shared__ unsigned short s_x [4096];   // x chunk [t][d]; attn after stage B; restaged at C end
  __shared__ unsigned short s_q [4096];   // q [t][e]
  __shared__ unsigned short s_k [4096];   // k [t'][e]
  __shared__ unsigned short s_kT[4096];   // phi(k)^T [e][t]
  __shared__ unsigned short s_vT[4096];   // v'^T [d][t]
  __shared__ unsigned short s_Sb[4096];   // S^T [d][e] snapshot (pre-update)

  const int tid = threadIdx.x, w = tid >> 6, lane = tid & 63, lr = lane & 15, lq = lane >> 4;
  const int bh = blockIdx.x, sg = blockIdx.y, b = bh >> 4, h = bh & 15;
  const float* xbase = x + ((size_t)b * Tc + (size_t)sg * SEGT) * Ec + h * Dc;
  float* obase = out + ((size_t)b * Tc + (size_t)sg * SEGT) * Ec + h * Dc;
  const unsigned short* wqT = wbuf;
  const unsigned short* wkT = wbuf + 4096;
  const unsigned short* wvoT = wbuf + 8192;
  const int sr = tid >> 2, sc = tid & 3;
  const f32x4 Z = {0.f, 0.f, 0.f, 0.f};

  // S-init: exclusive prefix over predecessor segment-KVs (P-layout, coalesced, L2-resident)
  f32x4 sacc[4] = {Z, Z, Z, Z};
  {
    const unsigned short* kvb = kvseg + (size_t)bh * NSEG * 4096 + (w * 64 + lane) * 16;
    for (int sp = 0; sp < sg; ++sp) {
      const unsigned short* p = kvb + (size_t)sp * 4096;
#pragma unroll
      for (int c = 0; c < 4; ++c) {
        uint2 u = *reinterpret_cast<const uint2*>(p + c * 4);
        sacc[c][0] += bf2f(u.x & 0xFFFFu); sacc[c][1] += bf2f(u.x >> 16);
        sacc[c][2] += bf2f(u.y & 0xFFFFu); sacc[c][3] += bf2f(u.y >> 16);
      }
    }
  }

  // weight fragments in registers
  short8 awq[2], awk[2], bwk[4][2], bwv[4][2];
#pragma unroll
  for (int kk = 0; kk < 2; ++kk) {
    awq[kk] = ld8(wqT + (w * 16 + lr) * 64 + kk * 32 + lq * 8);   // A-side rows e (w-strip)
    awk[kk] = ld8(wkT + (w * 16 + lr) * 64 + kk * 32 + lq * 8);
  }
#pragma unroll
  for (int c = 0; c < 4; ++c)
#pragma unroll
    for (int kk = 0; kk < 2; ++kk) {
      bwk[c][kk] = ld8(wkT + (c * 16 + lr) * 64 + kk * 32 + lq * 8);   // B-side rows e
      bwv[c][kk] = ld8(wvoT + (c * 16 + lr) * 64 + kk * 32 + lq * 8);  // B-side rows d
    }

  {  // stage chunk0 x -> LDS (swizzled)
    const float4* xf = (const float4*)(xbase + (size_t)sr * Ec + sc * 16);
    float4 f0 = xf[0], f1 = xf[1], f2 = xf[2], f3 = xf[3];
    *(short8*)sws(s_x, sr, sc * 32) = pk8(f0, f1);
    *(short8*)sws(s_x, sr, sc * 32 + 16) = pk8(f2, f3);
  }
  __syncthreads();  // x ready

#pragma unroll
  for (int ci = 0; ci < NCHUNK; ++ci) {
    // prefetch next chunk's x into regs (consumed at end of stage C)
    float4 pf0, pf1, pf2, pf3;
    if (ci < NCHUNK - 1) {
      const float4* xf = (const float4*)(xbase + (size_t)((ci + 1) * CHc + sr) * Ec + sc * 16);
      pf0 = xf[0]; pf1 = xf[1]; pf2 = xf[2]; pf3 = xf[3];
    }

    // ---- stage A: 4 projections; all stores transposed b64-packed ----
    short8 xb[4][2];
#pragma unroll
    for (int c = 0; c < 4; ++c) {
      xb[c][0] = ld8(sws(s_x, c * 16 + lr, lq * 16));
      xb[c][1] = ld8(sws(s_x, c * 16 + lr, 64 + lq * 16));
    }
    short8 xw0 = ld8(sws(s_x, w * 16 + lr, lq * 16));        // own strip (A-side)
    short8 xw1 = ld8(sws(s_x, w * 16 + lr, 64 + lq * 16));
#pragma unroll
    for (int c = 0; c < 4; ++c)                               // S snapshot -> s_Sb[d][e]
      st4(sws(s_Sb, c * 16 + lr, w * 32 + lq * 8), sacc[c][0], sacc[c][1], sacc[c][2], sacc[c][3]);

    f32x4 aqt[4] = {Z, Z, Z, Z}, akt[4] = {Z, Z, Z, Z}, ack[4] = {Z, Z, Z, Z}, acv[4] = {Z, Z, Z, Z};
    __builtin_amdgcn_s_setprio(1);
#pragma unroll
    for (int c = 0; c < 4; ++c) {
      aqt[c] = MFMA(awq[0], xb[c][0], aqt[c]); aqt[c] = MFMA(awq[1], xb[c][1], aqt[c]);  // qT[e][t]
      akt[c] = MFMA(awk[0], xb[c][0], akt[c]); akt[c] = MFMA(awk[1], xb[c][1], akt[c]);  // kT[e][t']
      ack[c] = MFMA(xw0, bwk[c][0], ack[c]);   ack[c] = MFMA(xw1, bwk[c][1], ack[c]);    // k[t][e]
      acv[c] = MFMA(xw0, bwv[c][0], acv[c]);   acv[c] = MFMA(xw1, bwv[c][1], acv[c]);    // v'[t][d]
    }
    __builtin_amdgcn_s_setprio(0);
#pragma unroll
    for (int c = 0; c < 4; ++c) {
      const int row = c * 16 + lr, cb = w * 32 + lq * 8;
      st4(sws(s_q, row, cb), phi_elu1(aqt[c][0]), phi_elu1(aqt[c][1]), phi_elu1(aqt[c][2]), phi_elu1(aqt[c][3]));
      st4(sws(s_k, row, cb), phi_elu1(akt[c][0]), phi_elu1(akt[c][1]), phi_elu1(akt[c][2]), phi_elu1(akt[c][3]));
      st4(sws(s_kT, row, cb), phi_elu1(ack[c][0]), phi_elu1(ack[c][1]), phi_elu1(ack[c][2]), phi_elu1(ack[c][3]));
      st4(sws(s_vT, row, cb), acv[c][0], acv[c][1], acv[c][2], acv[c][3]);
    }
    __syncthreads();  // B1

    // ---- stage B: attnT = k q^T (masked); o_inter = q@S; S += kT@v' ----
    short8 a_q0 = ld8(sws(s_q, w * 16 + lr, lq * 16));
    short8 a_q1 = ld8(sws(s_q, w * 16 + lr, 64 + lq * 16));
    short8 a_k0 = ld8(sws(s_k, w * 16 + lr, lq * 16));
    short8 a_k1 = ld8(sws(s_k, w * 16 + lr, 64 + lq * 16));
    short8 a_t0 = ld8(sws(s_kT, w * 16 + lr, lq * 16));
    short8 a_t1 = ld8(sws(s_kT, w * 16 + lr, 64 + lq * 16));
    f32x4 aat[4] = {Z, Z, Z, Z}, ao[4] = {Z, Z, Z, Z};
    __builtin_amdgcn_s_setprio(1);
#pragma unroll
    for (int c = 0; c < 4; ++c) {
      const int row = c * 16 + lr;
      aat[c]  = MFMA(a_k0, ld8(sws(s_q, row, lq * 16)), aat[c]);
      aat[c]  = MFMA(a_k1, ld8(sws(s_q, row, 64 + lq * 16)), aat[c]);
      ao[c]   = MFMA(a_q0, ld8(sws(s_Sb, row, lq * 16)), ao[c]);
      ao[c]   = MFMA(a_q1, ld8(sws(s_Sb, row, 64 + lq * 16)), ao[c]);
      sacc[c] = MFMA(a_t0, ld8(sws(s_vT, row, lq * 16)), sacc[c]);
      sacc[c] = MFMA(a_t1, ld8(sws(s_vT, row, 64 + lq * 16)), sacc[c]);
    }
    __builtin_amdgcn_s_setprio(0);
    // masked attnT (acc row t'=w16+lq*4+j, col t=c*16+lr) -> store attn[t][t'] into s_x
#pragma unroll
    for (int c = 0; c < 4; ++c) {
      int t = c * 16 + lr, tp = w * 16 + lq * 4;
      float m0 = (tp + 0 <= t) ? aat[c][0] : 0.f;
      float m1 = (tp + 1 <= t) ? aat[c][1] : 0.f;
      float m2 = (tp + 2 <= t) ? aat[c][2] : 0.f;
      float m3 = (tp + 3 <= t) ? aat[c][3] : 0.f;
      st4(sws(s_x, t, tp * 2), m0, m1, m2, m3);
    }
    __syncthreads();  // B2

    // ---- stage C: o += attn@v'; write out from fp32 acc; restage next x ----
    short8 a_a0 = ld8(sws(s_x, w * 16 + lr, lq * 16));
    short8 a_a1 = ld8(sws(s_x, w * 16 + lr, 64 + lq * 16));
    __builtin_amdgcn_s_setprio(1);
#pragma unroll
    for (int c = 0; c < 4; ++c) {
      const int row = c * 16 + lr;
      ao[c] = MFMA(a_a0, ld8(sws(s_vT, row, lq * 16)), ao[c]);
      ao[c] = MFMA(a_a1, ld8(sws(s_vT, row, 64 + lq * 16)), ao[c]);
    }
    __builtin_amdgcn_s_setprio(0);
    float* orow = obase + (size_t)(ci * CHc) * Ec;
#pragma unroll
    for (int c = 0; c < 4; ++c)
#pragma unroll
      for (int j = 0; j < 4; ++j)
        orow[(size_t)(w * 16 + lq * 4 + j) * Ec + c * 16 + lr] = ao[c][j];
    if (ci < NCHUNK - 1) {  // restage: per-wave row-disjoint, read-before-write in-wave
      *(short8*)sws(s_x, sr, sc * 32) = pk8(pf0, pf1);
      *(short8*)sws(s_x, sr, sc * 32 + 16) = pk8(pf2, pf3);
    }
    __syncthreads();  // B3
  }
}

extern "C" void kernel_launch(void* const* d_in, const int* in_sizes, int n_in,
                              void* d_out, int out_size, void* d_ws, size_t ws_size,
                              hipStream_t stream) {
  const float* x  = (const float*)d_in[0];
  const float* Wq = (const float*)d_in[1];
  const float* Wk = (const float*)d_in[2];
  const float* Wv = (const float*)d_in[3];
  const float* Wo = (const float*)d_in[4];
  float* out = (float*)d_out;

  unsigned short* wbuf  = (unsigned short*)d_ws;                   // 24 KB used (reserve 32 KB)
  unsigned short* kvseg = (unsigned short*)((char*)d_ws + 32768);  // 8 MB bf16, P-layout

  prep_weights<<<dim3(16), dim3(256), 0, stream>>>(Wq, Wk, Wv, Wo, wbuf);
  pass1_kvseg<<<dim3(64, NSEG - 1), dim3(256), 0, stream>>>(x, wbuf, kvseg);
  pass3_main<<<dim3(64, NSEG), dim3(256), 0, stream>>>(x, wbuf, kvseg, out);
}